// Round 6
// baseline (71.140 us; speedup 1.0000x reference)
//
#include <hip/hip_runtime.h>

// ---------------------------------------------------------------------------
// CausalFullAttention (decay-gated causal linear attention), MI355X gfx950
// b=2, n=2048, DIM=512, HEADS=8, DIM_HEAD=64
// R6: single-buffered 32KB GEMM (m97 structure — occupancy over pipeline
//     depth: 64KB dbuf capped us at 1-2 blocks/CU, m132 lesson), keeping
//     gload_lds w16, pre-swizzled src, XCD swizzle, shfl-csum epilogue.
// ---------------------------------------------------------------------------

using s8v   = __attribute__((ext_vector_type(8))) short;   // 8 x bf16 bits
using f32x4 = __attribute__((ext_vector_type(4))) float;

__device__ __forceinline__ unsigned short f2b(float f) {
  unsigned int u = __builtin_bit_cast(unsigned int, f);
  u += 0x7FFFu + ((u >> 16) & 1u);          // RNE
  return (unsigned short)(u >> 16);
}
__device__ __forceinline__ float b2f(unsigned short b) {
  unsigned int u = ((unsigned int)b) << 16;
  return __builtin_bit_cast(float, u);
}

__device__ __forceinline__ f32x4 mfma16(s8v a, s8v b, f32x4 c) {
  return __builtin_amdgcn_mfma_f32_16x16x32_bf16(a, b, c, 0, 0, 0);
}

// async global->LDS, 16B per lane; LDS dest must be wave-uniform base + lane*16
__device__ __forceinline__ void gload16(const void* g, void* l) {
  __builtin_amdgcn_global_load_lds(
      (const __attribute__((address_space(1))) void*)g,
      (__attribute__((address_space(3))) void*)l, 16, 0, 0);
}

// ---------------- 1) prep: rmsnorm (blocks 0-1023) + wtrans (1024-2303) -----
__global__ __launch_bounds__(256) void prep_k(const float* __restrict__ x,
                                              const float* __restrict__ gamma,
                                              short* __restrict__ xnb,
                                              const float* __restrict__ w_qkv,
                                              const float* __restrict__ w_a,
                                              const float* __restrict__ w_out,
                                              short* __restrict__ wT,
                                              short* __restrict__ woT) {
  __shared__ float t[32][33];
  int bid = blockIdx.x;
  if (bid < 1024) {
    int row  = bid * 4 + (threadIdx.x >> 6);
    int lane = threadIdx.x & 63;
    const float4* xp = reinterpret_cast<const float4*>(x + (size_t)row * 512 + lane * 8);
    float4 v0 = xp[0], v1 = xp[1];
    float ss = v0.x*v0.x + v0.y*v0.y + v0.z*v0.z + v0.w*v0.w
             + v1.x*v1.x + v1.y*v1.y + v1.z*v1.z + v1.w*v1.w;
#pragma unroll
    for (int off = 32; off > 0; off >>= 1) ss += __shfl_xor(ss, off, 64);
    float s = 22.627416997969522f / fmaxf(sqrtf(ss), 1e-12f);
    const float* g = gamma + lane * 8;
    float vals[8] = {v0.x, v0.y, v0.z, v0.w, v1.x, v1.y, v1.z, v1.w};
    s8v o;
#pragma unroll
    for (int j = 0; j < 8; ++j) o[j] = (short)f2b(vals[j] * s * g[j]);
    *reinterpret_cast<s8v*>(xnb + (size_t)row * 512 + lane * 8) = o;
  } else {
    int id = bid - 1024;
    int bx = id % 80, k0 = (id / 80) * 32;
    const float* src; short* dst; int N, n0;
    if (bx < 48)      { src = w_qkv; dst = wT;                      N = 1536; n0 = bx * 32; }
    else if (bx < 64) { src = w_a;   dst = wT + (size_t)1536 * 512; N = 512;  n0 = (bx - 48) * 32; }
    else              { src = w_out; dst = woT;                     N = 512;  n0 = (bx - 64) * 32; }
    int tx = threadIdx.x & 31, ty = threadIdx.x >> 5;
#pragma unroll
    for (int i = 0; i < 4; ++i)
      t[ty + 8 * i][tx] = src[(size_t)(k0 + ty + 8 * i) * N + n0 + tx];
    __syncthreads();
#pragma unroll
    for (int i = 0; i < 4; ++i)
      dst[(size_t)(n0 + ty + 8 * i) * 512 + k0 + tx] = (short)f2b(t[tx][ty + 8 * i]);
  }
}

// ---------------- 2/6) GEMM: C = A[M][K] * B[N][K]^T (+bias), single-buf -----
// m97 structure: stage -> sync -> compute -> sync. 32KB LDS at 128x128.
// EPI=0: cols<1536 -> qkvb bf16 [3][b][h][n][64]; cols>=1536 -> araw fp32
//        [b][h][n][64] + per-chunk csum of log(clip(sigmoid)) via shfl.
// EPI=1: fp32 C[row*N+col] + bias0[col]
template <int BM, int BN, int EPI>
__global__ __launch_bounds__(256) void gemm_bt(const short* __restrict__ A,
                                               const short* __restrict__ Bm,
                                               void* __restrict__ Cout,
                                               const float* __restrict__ bias0,
                                               const float* __restrict__ bias1,
                                               float* __restrict__ araw,
                                               float* __restrict__ csum,
                                               int M, int N, int K) {
  __shared__ __align__(16) char LA[BM * 128];
  __shared__ __align__(16) char LB[BN * 128];
  constexpr int WM = BM / 2, WN = BN / 2, FM = WM / 16, FN = WN / 16;
  const int tid = threadIdx.x, lane = tid & 63, wave = tid >> 6;
  const int wr = (wave >> 1) * WM, wc = (wave & 1) * WN;
  // XCD-aware bijective swizzle: each XCD gets a contiguous by-stripe
  int orig = blockIdx.y * gridDim.x + blockIdx.x;
  int xcd = orig & 7, rq = orig >> 3;
  int bx = rq % gridDim.x;
  int by = xcd * (gridDim.y >> 3) + rq / gridDim.x;
  const int m0 = by * BM, n0 = bx * BN;
  const int NS = K / 64;

  auto stage = [&](int k0) {
#pragma unroll
    for (int r = 0; r < BM / 32; ++r) {
      int o = r * 4096 + tid * 16;
      int row = o >> 7;
      int ce = (((o & 127) ^ ((row & 7) << 4)) >> 1);   // pre-swizzled src col
      gload16(A + (size_t)(m0 + row) * K + k0 + ce, LA + o);
    }
#pragma unroll
    for (int r = 0; r < BN / 32; ++r) {
      int o = r * 4096 + tid * 16;
      int row = o >> 7;
      int ce = (((o & 127) ^ ((row & 7) << 4)) >> 1);
      gload16(Bm + (size_t)(n0 + row) * K + k0 + ce, LB + o);
    }
  };

  f32x4 acc[FM][FN] = {};
  for (int t = 0; t < NS; ++t) {
    stage(t * 64);
    __syncthreads();                 // vmcnt(0) drained: tile ready
#pragma unroll
    for (int kk = 0; kk < 2; ++kk) {
      s8v af[FM], bf[FN];
#pragma unroll
      for (int m = 0; m < FM; ++m) {
        int row = wr + m * 16 + (lane & 15);
        int ad = ((row << 7) + kk * 64 + ((lane >> 4) << 4)) ^ ((row & 7) << 4);
        af[m] = *reinterpret_cast<const s8v*>(LA + ad);
      }
#pragma unroll
      for (int n = 0; n < FN; ++n) {
        int row = wc + n * 16 + (lane & 15);
        int ad = ((row << 7) + kk * 64 + ((lane >> 4) << 4)) ^ ((row & 7) << 4);
        bf[n] = *reinterpret_cast<const s8v*>(LB + ad);
      }
#pragma unroll
      for (int m = 0; m < FM; ++m)
#pragma unroll
        for (int n = 0; n < FN; ++n)
          acc[m][n] = mfma16(af[m], bf[n], acc[m][n]);
    }
    if (t + 1 < NS) __syncthreads(); // reads done before next stage overwrites
  }

  if constexpr (EPI == 0) {
    short* qkvb = (short*)Cout;
    if (n0 < 1536) {
#pragma unroll
      for (int m = 0; m < FM; ++m)
#pragma unroll
        for (int n = 0; n < FN; ++n)
#pragma unroll
          for (int r = 0; r < 4; ++r) {
            int row = m0 + wr + m * 16 + ((lane >> 4) << 2) + r;
            int col = n0 + wc + n * 16 + (lane & 15);
            float v = acc[m][n][r] + bias0[col];
            int w = col >> 9, h = (col >> 6) & 7, d = col & 63;
            int b = row >> 11, nn = row & 2047;
            qkvb[((((size_t)(w * 2 + b)) * 8 + h) * 2048 + nn) * 64 + d] = (short)f2b(v);
          }
    } else {
      // gate path: write fp32 araw + per-chunk csum via in-register shfl reduce
      float cs[FN] = {};
      int b = m0 >> 11;
#pragma unroll
      for (int m = 0; m < FM; ++m)
#pragma unroll
        for (int n = 0; n < FN; ++n)
#pragma unroll
          for (int r = 0; r < 4; ++r) {
            int row = m0 + wr + m * 16 + ((lane >> 4) << 2) + r;
            int gc = n0 + wc + n * 16 + (lane & 15) - 1536;
            int h = gc >> 6, d = gc & 63, nn = row & 2047;
            float xv = acc[m][n][r] + bias1[gc];
            araw[((size_t)(b * 8 + h) * 2048 + nn) * 64 + d] = xv;
            float a = 1.f / (1.f + expf(-xv));
            a = fminf(fmaxf(a, 1e-10f), 1.f);
            cs[n] += logf(a);
          }
#pragma unroll
      for (int n = 0; n < FN; ++n) {
        cs[n] += __shfl_xor(cs[n], 16, 64);
        cs[n] += __shfl_xor(cs[n], 32, 64);
      }
      int nsel = lane >> 4;
      float v = (nsel == 0) ? cs[0] : (nsel == 1) ? cs[1] : (nsel == 2) ? cs[2] : cs[3];
      int col = wc + nsel * 16 + (lane & 15);
      int gc = n0 + col - 1536;
      int h = gc >> 6, d = gc & 63;
      int chunkg = ((m0 & 2047) >> 6) + (wave >> 1);   // chunk within batch
      csum[(((size_t)(b * 8 + h)) * 32 + chunkg) * 64 + d] = v;
    }
  } else {
    float* C = (float*)Cout;
#pragma unroll
    for (int m = 0; m < FM; ++m)
#pragma unroll
      for (int n = 0; n < FN; ++n)
#pragma unroll
        for (int r = 0; r < 4; ++r) {
          int row = m0 + wr + m * 16 + ((lane >> 4) << 2) + r;
          int col = n0 + wc + n * 16 + (lane & 15);
          C[(size_t)row * N + col] = acc[m][n][r] + bias0[col];
        }
  }
}

// ---------------- 3) scan2: gates -> q2,k2,vT + folded kstate ----------------
__global__ __launch_bounds__(256) void scan2_k(const short* __restrict__ qkvb,
                                               const float* __restrict__ araw,
                                               const float* __restrict__ csum,
                                               short* __restrict__ q2,
                                               short* __restrict__ k2,
                                               short* __restrict__ vT,
                                               short* __restrict__ Sbuf) {
  int chunk = blockIdx.x, bh = blockIdx.y;
  int tid = threadIdx.x, lane = tid & 63, wave = tid >> 6;
  int d = lane;
  __shared__ short kL[64][72], vL[64][72];
  __shared__ float wsum[4][64];
  __shared__ __align__(16) char kT[8192], vTl[8192];
  // chunk prefix from csum
  float pre = 0.f;
  for (int c = 0; c < chunk; ++c) pre += csum[((size_t)bh * 32 + c) * 64 + d];
  // local log-cumsum of this wave's 16 rows (recompute gates from araw)
  const float* ap = araw + ((size_t)bh * 2048 + chunk * 64 + wave * 16) * 64 + d;
  float la[16]; float run = 0.f;
#pragma unroll
  for (int rr = 0; rr < 16; ++rr) {
    float xv = ap[rr * 64];
    float a = 1.f / (1.f + expf(-xv));
    a = fminf(fmaxf(a, 1e-10f), 1.f);
    run += logf(a);
    la[rr] = run;
  }
  wsum[wave][d] = run;
  __syncthreads();
#pragma unroll
  for (int w = 0; w < 3; ++w) if (w < wave) pre += wsum[w][d];
  // gates + q2/k2 + LDS row staging
  const size_t WS = (size_t)2 * 8 * 2048 * 64;
  size_t base = ((size_t)bh * 2048 + chunk * 64 + wave * 16) * 64 + d;
#pragma unroll 4
  for (int rr = 0; rr < 16; ++rr) {
    int r = wave * 16 + rr;
    float g = expf(pre + la[rr]);            // a_cum
    float gi = 1.f / fmaxf(g, 1e-8f);        // a_cum_inv
    float qv = b2f((unsigned short)qkvb[base + rr * 64]);
    float kv = b2f((unsigned short)qkvb[base + WS + rr * 64]);
    short vb = qkvb[base + 2 * WS + rr * 64];
    q2[base + rr * 64] = (short)f2b(qv * 0.125f * g);   // SCALE = 64^-0.5
    unsigned short kb = f2b(kv * gi);
    k2[base + rr * 64] = (short)kb;
    kL[r][d] = (short)kb;
    vL[r][d] = vb;
  }
  __syncthreads();
  // transpose to global vT and to LDS [d][j] tiles (XOR-swizzled) for kstate
  short* vTrow = vT + ((size_t)bh * 64 + d) * 2048 + chunk * 64;
#pragma unroll
  for (int gg = 0; gg < 2; ++gg) {
    int g8 = wave + gg * 4;
    s8v pk, pv;
#pragma unroll
    for (int j = 0; j < 8; ++j) { pk[j] = kL[g8 * 8 + j][d]; pv[j] = vL[g8 * 8 + j][d]; }
    *reinterpret_cast<s8v*>(vTrow + g8 * 8) = pv;
    int ad = ((d << 7) + g8 * 16) ^ ((d & 7) << 4);
    *reinterpret_cast<s8v*>(kT  + ad) = pk;
    *reinterpret_cast<s8v*>(vTl + ad) = pv;
  }
  __syncthreads();
  // kstate: wave w computes S rows [w*16,w*16+16): S[d][d'] = sum_j V[j][d] k2[j][d']
  f32x4 acc[4] = {};
#pragma unroll
  for (int kk = 0; kk < 2; ++kk) {
    int arow = wave * 16 + (lane & 15);
    int aad = ((arow << 7) + kk * 64 + ((lane >> 4) << 4)) ^ ((arow & 7) << 4);
    s8v av = *reinterpret_cast<const s8v*>(vTl + aad);
#pragma unroll
    for (int n = 0; n < 4; ++n) {
      int brow = n * 16 + (lane & 15);
      int bad = ((brow << 7) + kk * 64 + ((lane >> 4) << 4)) ^ ((brow & 7) << 4);
      acc[n] = mfma16(av, *reinterpret_cast<const s8v*>(kT + bad), acc[n]);
    }
  }
  short* Sp = Sbuf + ((size_t)bh * 32 + chunk) * 4096;
#pragma unroll
  for (int n = 0; n < 4; ++n)
#pragma unroll
    for (int r = 0; r < 4; ++r)
      Sp[(wave * 16 + ((lane >> 4) << 2) + r) * 64 + n * 16 + (lane & 15)] = (short)f2b(acc[n][r]);
}

// ---------------- 4) sprefix: exclusive prefix of states (fp32 acc, bf16 io) -
__global__ __launch_bounds__(256) void sprefix_k(const short* __restrict__ Sbuf,
                                                 short* __restrict__ Spre) {
  int bh = blockIdx.x >> 4;
  int e = ((blockIdx.x & 15) << 8) + threadIdx.x;
  size_t base = (size_t)bh * 32 * 4096 + e;
  float acc = 0.f;
  for (int c = 0; c < 32; ++c) {
    Spre[base + (size_t)c * 4096] = (short)f2b(acc);
    acc += b2f((unsigned short)Sbuf[base + (size_t)c * 4096]);
  }
}

// ---------------- 5) attnk: out = q2@Spre + tril(q2 k2^T)@v ------------------
__global__ __launch_bounds__(256) void attnk_k(const short* __restrict__ q2,
                                               const short* __restrict__ k2,
                                               const short* __restrict__ vT,
                                               const short* __restrict__ Spre,
                                               short* __restrict__ aout) {
  int chunk = blockIdx.x, bh = blockIdx.y;
  int tid = threadIdx.x, lane = tid & 63, wave = tid >> 6;
  __shared__ __align__(16) char LQ[8192], LK[8192], LV[8192], LS[8192], LP[8192];
#pragma unroll
  for (int rr = 0; rr < 2; ++rr) {
    int o = rr * 4096 + tid * 16;
    int row = o >> 7;
    int ce = (((o & 127) ^ ((row & 7) << 4)) >> 1);
    gload16(q2   + ((size_t)bh * 2048 + chunk * 64 + row) * 64 + ce, LQ + o);
    gload16(k2   + ((size_t)bh * 2048 + chunk * 64 + row) * 64 + ce, LK + o);
    gload16(vT   + ((size_t)bh * 64 + row) * 2048 + chunk * 64 + ce, LV + o);
    gload16(Spre + (((size_t)bh * 32 + chunk) * 64 + row) * 64 + ce, LS + o);
  }
  __syncthreads();
  f32x4 accS[4] = {}, accO[4] = {};
#pragma unroll
  for (int kk = 0; kk < 2; ++kk) {
    int arow = wave * 16 + (lane & 15);
    int aad = ((arow << 7) + kk * 64 + ((lane >> 4) << 4)) ^ ((arow & 7) << 4);
    s8v aq = *reinterpret_cast<const s8v*>(LQ + aad);
#pragma unroll
    for (int n = 0; n < 4; ++n) {
      int brow = n * 16 + (lane & 15);
      int bad = ((brow << 7) + kk * 64 + ((lane >> 4) << 4)) ^ ((brow & 7) << 4);
      accS[n] = mfma16(aq, *reinterpret_cast<const s8v*>(LK + bad), accS[n]);
      accO[n] = mfma16(aq, *reinterpret_cast<const s8v*>(LS + bad), accO[n]);
    }
  }
  // causal mask within chunk, write P (bf16, swizzled)
#pragma unroll
  for (int n = 0; n < 4; ++n)
#pragma unroll
    for (int r = 0; r < 4; ++r) {
      int i = wave * 16 + ((lane >> 4) << 2) + r;
      int j = n * 16 + (lane & 15);
      float v = (j <= i) ? accS[n][r] : 0.f;
      int ad = ((i << 7) + (j << 1)) ^ ((i & 7) << 4);
      *reinterpret_cast<short*>(LP + ad) = (short)f2b(v);
    }
  __syncthreads();
#pragma unroll
  for (int kk = 0; kk < 2; ++kk) {
    int arow = wave * 16 + (lane & 15);
    int aad = ((arow << 7) + kk * 64 + ((lane >> 4) << 4)) ^ ((arow & 7) << 4);
    s8v ap = *reinterpret_cast<const s8v*>(LP + aad);
#pragma unroll
    for (int n = 0; n < 4; ++n) {
      int brow = n * 16 + (lane & 15);
      int bad = ((brow << 7) + kk * 64 + ((lane >> 4) << 4)) ^ ((brow & 7) << 4);
      accO[n] = mfma16(ap, *reinterpret_cast<const s8v*>(LV + bad), accO[n]);
    }
  }
  int b = bh >> 3, h = bh & 7;
#pragma unroll
  for (int n = 0; n < 4; ++n)
#pragma unroll
    for (int r = 0; r < 4; ++r) {
      int i = wave * 16 + ((lane >> 4) << 2) + r;
      int col = h * 64 + n * 16 + (lane & 15);
      size_t row = (size_t)b * 2048 + chunk * 64 + i;
      aout[row * 512 + col] = (short)f2b(accO[n][r]);
    }
}

// ---------------------------------------------------------------------------
extern "C" void kernel_launch(void* const* d_in, const int* in_sizes, int n_in,
                              void* d_out, int out_size, void* d_ws, size_t ws_size,
                              hipStream_t stream) {
  const float* x     = (const float*)d_in[0];
  const float* gamma = (const float*)d_in[1];
  const float* w_qkv = (const float*)d_in[2];
  const float* b_qkv = (const float*)d_in[3];
  const float* w_a   = (const float*)d_in[4];
  const float* b_a   = (const float*)d_in[5];
  const float* w_out = (const float*)d_in[6];
  const float* b_out = (const float*)d_in[7];
  float* out = (float*)d_out;
  char* ws = (char*)d_ws;

  const size_t MB = 1u << 20;
  short* xnb  = (short*)(ws);                 // 4 MiB   [4096][512] bf16
  short* wT   = (short*)(ws + 4  * MB);       // 2 MiB   [2048][512] bf16
  short* woT  = (short*)(ws + 6  * MB);       // 0.5 MiB [512][512]  bf16
  short* qkvb = (short*)(ws + 7  * MB);       // 12 MiB  [3][2][8][2048][64] bf16
  float* araw = (float*)(ws + 19 * MB);       // 8 MiB   [16][2048][64] f32
  float* csum = (float*)(ws + 27 * MB);       // 128 KiB [16][32][64] f32
  short* q2   = (short*)(ws + 28 * MB);       // 4 MiB   [16][2048][64] bf16
  short* k2   = (short*)(ws + 32 * MB);       // 4 MiB
  short* vT   = (short*)(ws + 36 * MB);       // 4 MiB   [16][64][2048]
  short* Sbuf = (short*)(ws + 40 * MB);       // 4 MiB   [16][32][64][64] bf16
  short* Spre = (short*)(ws + 44 * MB);       // 4 MiB
  short* aout = (short*)(ws + 48 * MB);       // 4 MiB   [4096][512] bf16

  prep_k<<<2304, 256, 0, stream>>>(x, gamma, xnb, w_qkv, w_a, w_out, wT, woT);

  gemm_bt<128, 128, 0><<<dim3(16, 32), 256, 0, stream>>>(
      xnb, wT, qkvb, b_qkv, b_a, araw, csum, 4096, 2048, 512);

  scan2_k<<<dim3(32, 16), 256, 0, stream>>>(qkvb, araw, csum, q2, k2, vT, Sbuf);

  sprefix_k<<<256, 256, 0, stream>>>(Sbuf, Spre);
  attnk_k<<<dim3(32, 16), 256, 0, stream>>>(q2, k2, vT, Spre, aout);

  gemm_bt<64, 64, 1><<<dim3(8, 64), 256, 0, stream>>>(
      aout, woT, out, b_out, b_out, nullptr, nullptr, 4096, 512, 512);
}

// Round 8
// 70.981 us; speedup vs baseline: 1.0022x; 1.0022x over previous
//
#include <hip/hip_runtime.h>
#include <hip/hip_cooperative_groups.h>

// ---------------------------------------------------------------------------
// CausalFullAttention (decay-gated causal linear attention), MI355X gfx950
// b=2, n=2048, DIM=512, HEADS=8, DIM_HEAD=64
// R8: cooperative mega-kernel, arena trimmed to 32KB (2 blocks/CU under the
//     conservative 64KB-LDS occupancy model), launch pre-gated by attribute +
//     occupancy query, with a 6-kernel fallback sharing the same __device__
//     stage functions (identical math either way).
// ---------------------------------------------------------------------------

namespace cg = cooperative_groups;

using s8v   = __attribute__((ext_vector_type(8))) short;   // 8 x bf16 bits
using f32x4 = __attribute__((ext_vector_type(4))) float;

__device__ __forceinline__ unsigned short f2b(float f) {
  unsigned int u = __builtin_bit_cast(unsigned int, f);
  u += 0x7FFFu + ((u >> 16) & 1u);          // RNE
  return (unsigned short)(u >> 16);
}
__device__ __forceinline__ float b2f(unsigned short b) {
  unsigned int u = ((unsigned int)b) << 16;
  return __builtin_bit_cast(float, u);
}
__device__ __forceinline__ f32x4 mfma16(s8v a, s8v b, f32x4 c) {
  return __builtin_amdgcn_mfma_f32_16x16x32_bf16(a, b, c, 0, 0, 0);
}
__device__ __forceinline__ void gload16(const void* g, void* l) {
  __builtin_amdgcn_global_load_lds(
      (const __attribute__((address_space(1))) void*)g,
      (__attribute__((address_space(3))) void*)l, 16, 0, 0);
}

// ---------------- stage: prep (rmsnorm u<1024 | wtrans u>=1024) --------------
__device__ __forceinline__ void st_prep(int u, int tid, char* arena,
    const float* __restrict__ x, const float* __restrict__ gamma,
    short* __restrict__ xnb,
    const float* __restrict__ w_qkv, const float* __restrict__ w_a,
    const float* __restrict__ w_out,
    short* __restrict__ wT, short* __restrict__ woT) {
  int lane = tid & 63, wave = tid >> 6;
  if (u < 1024) {
    int row = u * 4 + wave;
    const float4* xp = reinterpret_cast<const float4*>(x + (size_t)row * 512 + lane * 8);
    float4 v0 = xp[0], v1 = xp[1];
    float ss = v0.x*v0.x + v0.y*v0.y + v0.z*v0.z + v0.w*v0.w
             + v1.x*v1.x + v1.y*v1.y + v1.z*v1.z + v1.w*v1.w;
#pragma unroll
    for (int off = 32; off > 0; off >>= 1) ss += __shfl_xor(ss, off, 64);
    float s = 22.627416997969522f / fmaxf(sqrtf(ss), 1e-12f);
    const float* g = gamma + lane * 8;
    float vals[8] = {v0.x, v0.y, v0.z, v0.w, v1.x, v1.y, v1.z, v1.w};
    s8v o;
#pragma unroll
    for (int j = 0; j < 8; ++j) o[j] = (short)f2b(vals[j] * s * g[j]);
    *reinterpret_cast<s8v*>(xnb + (size_t)row * 512 + lane * 8) = o;
  } else {
    float (*t)[33] = reinterpret_cast<float (*)[33]>(arena);
    int id = u - 1024;
    int bx = id % 80, k0 = (id / 80) * 32;
    const float* src; short* dst; int N, n0;
    if (bx < 48)      { src = w_qkv; dst = wT;                      N = 1536; n0 = bx * 32; }
    else if (bx < 64) { src = w_a;   dst = wT + (size_t)1536 * 512; N = 512;  n0 = (bx - 48) * 32; }
    else              { src = w_out; dst = woT;                     N = 512;  n0 = (bx - 64) * 32; }
    int tx = tid & 31, ty = tid >> 5;
    __syncthreads();   // prior arena use complete
#pragma unroll
    for (int i = 0; i < 4; ++i)
      t[ty + 8 * i][tx] = src[(size_t)(k0 + ty + 8 * i) * N + n0 + tx];
    __syncthreads();
#pragma unroll
    for (int i = 0; i < 4; ++i)
      dst[(size_t)(n0 + ty + 8 * i) * 512 + k0 + tx] = (short)f2b(t[tx][ty + 8 * i]);
  }
}

// ---------------- shared single-buffered GEMM core (m97 structure) -----------
template <int BM, int BN, int FM, int FN>
__device__ __forceinline__ void gemm_core(const short* __restrict__ A,
                                          const short* __restrict__ Bm,
                                          char* LA, char* LB,
                                          int m0, int n0, int tid,
                                          f32x4 (&acc)[FM][FN]) {
  const int lane = tid & 63, wave = tid >> 6;
  const int wr = (wave >> 1) * (BM / 2), wc = (wave & 1) * (BN / 2);
#pragma unroll 1
  for (int t = 0; t < 8; ++t) {            // K = 512, BK = 64
    const int k0 = t * 64;
#pragma unroll
    for (int r = 0; r < BM / 32; ++r) {
      int o = r * 4096 + tid * 16;
      int row = o >> 7;
      int ce = (((o & 127) ^ ((row & 7) << 4)) >> 1);   // pre-swizzled src col
      gload16(A + (size_t)(m0 + row) * 512 + k0 + ce, LA + o);
    }
#pragma unroll
    for (int r = 0; r < BN / 32; ++r) {
      int o = r * 4096 + tid * 16;
      int row = o >> 7;
      int ce = (((o & 127) ^ ((row & 7) << 4)) >> 1);
      gload16(Bm + (size_t)(n0 + row) * 512 + k0 + ce, LB + o);
    }
    __syncthreads();                       // tile ready (vmcnt drained)
#pragma unroll
    for (int kk = 0; kk < 2; ++kk) {
      s8v af[FM], bf[FN];
#pragma unroll
      for (int m = 0; m < FM; ++m) {
        int row = wr + m * 16 + (lane & 15);
        int ad = ((row << 7) + kk * 64 + ((lane >> 4) << 4)) ^ ((row & 7) << 4);
        af[m] = *reinterpret_cast<const s8v*>(LA + ad);
      }
#pragma unroll
      for (int n = 0; n < FN; ++n) {
        int row = wc + n * 16 + (lane & 15);
        int ad = ((row << 7) + kk * 64 + ((lane >> 4) << 4)) ^ ((row & 7) << 4);
        bf[n] = *reinterpret_cast<const s8v*>(LB + ad);
      }
#pragma unroll
      for (int m = 0; m < FM; ++m)
#pragma unroll
        for (int n = 0; n < FN; ++n)
          acc[m][n] = mfma16(af[m], bf[n], acc[m][n]);
    }
    if (t + 1 < 8) __syncthreads();        // reads done before next overwrite
  }
}

// ---------------- stage: gemm<0> + qkv/gate epilogue -------------------------
__device__ __forceinline__ void st_gemm0(int vid, int tid, char* arena,
    const short* __restrict__ xnb, const short* __restrict__ wT,
    short* __restrict__ qkvb, const float* __restrict__ b_qkv,
    const float* __restrict__ b_a, float* __restrict__ araw,
    float* __restrict__ csum) {
  const int lane = tid & 63, wave = tid >> 6;
  int xcd = vid & 7, rq = vid >> 3;
  int bx = rq & 15, by = xcd * 4 + (rq >> 4);      // bijective XCD swizzle
  int m0 = by * 128, n0 = bx * 128;
  f32x4 acc[4][4] = {};
  gemm_core<128, 128, 4, 4>(xnb, wT, arena, arena + 16384, m0, n0, tid, acc);
  int wr = (wave >> 1) * 64, wc = (wave & 1) * 64;
  if (n0 < 1536) {
#pragma unroll
    for (int m = 0; m < 4; ++m)
#pragma unroll
      for (int n = 0; n < 4; ++n)
#pragma unroll
        for (int r = 0; r < 4; ++r) {
          int row = m0 + wr + m * 16 + ((lane >> 4) << 2) + r;
          int col = n0 + wc + n * 16 + (lane & 15);
          float v = acc[m][n][r] + b_qkv[col];
          int w = col >> 9, h = (col >> 6) & 7, d = col & 63;
          int b = row >> 11, nn = row & 2047;
          qkvb[((((size_t)(w * 2 + b)) * 8 + h) * 2048 + nn) * 64 + d] = (short)f2b(v);
        }
  } else {
    float cs[4] = {};
    int b = m0 >> 11;
#pragma unroll
    for (int m = 0; m < 4; ++m)
#pragma unroll
      for (int n = 0; n < 4; ++n)
#pragma unroll
        for (int r = 0; r < 4; ++r) {
          int row = m0 + wr + m * 16 + ((lane >> 4) << 2) + r;
          int gc = n0 + wc + n * 16 + (lane & 15) - 1536;
          int h = gc >> 6, d = gc & 63, nn = row & 2047;
          float xv = acc[m][n][r] + b_a[gc];
          araw[((size_t)(b * 8 + h) * 2048 + nn) * 64 + d] = xv;
          float a = 1.f / (1.f + expf(-xv));
          a = fminf(fmaxf(a, 1e-10f), 1.f);
          cs[n] += logf(a);
        }
#pragma unroll
    for (int n = 0; n < 4; ++n) {
      cs[n] += __shfl_xor(cs[n], 16, 64);
      cs[n] += __shfl_xor(cs[n], 32, 64);
    }
    int nsel = lane >> 4;
    float v = (nsel == 0) ? cs[0] : (nsel == 1) ? cs[1] : (nsel == 2) ? cs[2] : cs[3];
    int col = wc + nsel * 16 + (lane & 15);
    int gc = n0 + col - 1536;
    int h = gc >> 6, d = gc & 63;
    int chunkg = ((m0 & 2047) >> 6) + (wave >> 1);
    csum[(((size_t)(b * 8 + h)) * 32 + chunkg) * 64 + d] = v;
  }
}

// ---------------- stage: scan2 (gates + q2/k2/vT + kstate), 32KB arena -------
__device__ __forceinline__ void st_scan2(int vid, int tid, char* arena,
    const short* __restrict__ qkvb, const float* __restrict__ araw,
    const float* __restrict__ csum, short* __restrict__ q2,
    short* __restrict__ k2, short* __restrict__ vT, short* __restrict__ Sbuf) {
  int chunk = vid & 31, bh = vid >> 5;
  int lane = tid & 63, wave = tid >> 6, d = lane;
  short (*kL)[64] = reinterpret_cast<short (*)[64]>(arena);            // 8 KiB
  short (*vL)[64] = reinterpret_cast<short (*)[64]>(arena + 8192);     // 8 KiB
  char* kT  = arena + 16384;                                           // 8 KiB
  char* vTl = arena + 24576;                                           // 8 KiB
  float (*wsum)[64] = reinterpret_cast<float (*)[64]>(arena + 16384);  // aliases kT
  float pre = 0.f;
  for (int c = 0; c < chunk; ++c) pre += csum[((size_t)bh * 32 + c) * 64 + d];
  const float* ap = araw + ((size_t)bh * 2048 + chunk * 64 + wave * 16) * 64 + d;
  float la[16]; float run = 0.f;
#pragma unroll
  for (int rr = 0; rr < 16; ++rr) {
    float xv = ap[rr * 64];
    float a = 1.f / (1.f + expf(-xv));
    a = fminf(fmaxf(a, 1e-10f), 1.f);
    run += logf(a);
    la[rr] = run;
  }
  wsum[wave][d] = run;
  __syncthreads();
#pragma unroll
  for (int w = 0; w < 3; ++w) if (w < wave) pre += wsum[w][d];
  const size_t WS = (size_t)2 * 8 * 2048 * 64;
  size_t base = ((size_t)bh * 2048 + chunk * 64 + wave * 16) * 64 + d;
#pragma unroll 4
  for (int rr = 0; rr < 16; ++rr) {
    int r = wave * 16 + rr;
    float g = expf(pre + la[rr]);            // a_cum
    float gi = 1.f / fmaxf(g, 1e-8f);        // a_cum_inv
    float qv = b2f((unsigned short)qkvb[base + rr * 64]);
    float kv = b2f((unsigned short)qkvb[base + WS + rr * 64]);
    short vb = qkvb[base + 2 * WS + rr * 64];
    q2[base + rr * 64] = (short)f2b(qv * 0.125f * g);   // SCALE = 64^-0.5
    unsigned short kb = f2b(kv * gi);
    k2[base + rr * 64] = (short)kb;
    kL[r][d] = (short)kb;
    vL[r][d] = vb;
  }
  __syncthreads();   // kL/vL ready; all wsum reads done (kT overwrite safe)
  short* vTrow = vT + ((size_t)bh * 64 + d) * 2048 + chunk * 64;
#pragma unroll
  for (int gg = 0; gg < 2; ++gg) {
    int g8 = wave + gg * 4;
    s8v pk, pv;
#pragma unroll
    for (int j = 0; j < 8; ++j) { pk[j] = kL[g8 * 8 + j][d]; pv[j] = vL[g8 * 8 + j][d]; }
    *reinterpret_cast<s8v*>(vTrow + g8 * 8) = pv;
    int ad = ((d << 7) + g8 * 16) ^ ((d & 7) << 4);
    *reinterpret_cast<s8v*>(kT  + ad) = pk;
    *reinterpret_cast<s8v*>(vTl + ad) = pv;
  }
  __syncthreads();
  f32x4 acc[4] = {};
#pragma unroll
  for (int kk = 0; kk < 2; ++kk) {
    int arow = wave * 16 + (lane & 15);
    int aad = ((arow << 7) + kk * 64 + ((lane >> 4) << 4)) ^ ((arow & 7) << 4);
    s8v av = *reinterpret_cast<const s8v*>(vTl + aad);
#pragma unroll
    for (int n = 0; n < 4; ++n) {
      int brow = n * 16 + (lane & 15);
      int bad = ((brow << 7) + kk * 64 + ((lane >> 4) << 4)) ^ ((brow & 7) << 4);
      acc[n] = mfma16(av, *reinterpret_cast<const s8v*>(kT + bad), acc[n]);
    }
  }
  short* Sp = Sbuf + ((size_t)bh * 32 + chunk) * 4096;
#pragma unroll
  for (int n = 0; n < 4; ++n)
#pragma unroll
    for (int r = 0; r < 4; ++r)
      Sp[(wave * 16 + ((lane >> 4) << 2) + r) * 64 + n * 16 + (lane & 15)] = (short)f2b(acc[n][r]);
}

// ---------------- stage: sprefix ---------------------------------------------
__device__ __forceinline__ void st_sprefix(int vid, int tid,
    const short* __restrict__ Sbuf, short* __restrict__ Spre) {
  int bh = vid >> 4;
  int e = ((vid & 15) << 8) + tid;
  size_t base = (size_t)bh * 32 * 4096 + e;
  float acc = 0.f;
  for (int c = 0; c < 32; ++c) {
    Spre[base + (size_t)c * 4096] = (short)f2b(acc);
    acc += b2f((unsigned short)Sbuf[base + (size_t)c * 4096]);
  }
}

// ---------------- stage: attnk (32KB arena: P reuses LQ) ---------------------
__device__ __forceinline__ void st_attnk(int vid, int tid, char* arena,
    const short* __restrict__ q2, const short* __restrict__ k2,
    const short* __restrict__ vT, const short* __restrict__ Spre,
    short* __restrict__ aout) {
  int chunk = vid & 31, bh = vid >> 5;
  int lane = tid & 63, wave = tid >> 6;
  char* LQ = arena;              // later reused for P
  char* LK = arena + 8192;
  char* LV = arena + 16384;
  char* LS = arena + 24576;
#pragma unroll
  for (int rr = 0; rr < 2; ++rr) {
    int o = rr * 4096 + tid * 16;
    int row = o >> 7;
    int ce = (((o & 127) ^ ((row & 7) << 4)) >> 1);
    gload16(q2   + ((size_t)bh * 2048 + chunk * 64 + row) * 64 + ce, LQ + o);
    gload16(k2   + ((size_t)bh * 2048 + chunk * 64 + row) * 64 + ce, LK + o);
    gload16(vT   + ((size_t)bh * 64 + row) * 2048 + chunk * 64 + ce, LV + o);
    gload16(Spre + (((size_t)bh * 32 + chunk) * 64 + row) * 64 + ce, LS + o);
  }
  __syncthreads();
  f32x4 accS[4] = {}, accO[4] = {};
#pragma unroll
  for (int kk = 0; kk < 2; ++kk) {
    int arow = wave * 16 + (lane & 15);
    int aad = ((arow << 7) + kk * 64 + ((lane >> 4) << 4)) ^ ((arow & 7) << 4);
    s8v aq = *reinterpret_cast<const s8v*>(LQ + aad);
#pragma unroll
    for (int n = 0; n < 4; ++n) {
      int brow = n * 16 + (lane & 15);
      int bad = ((brow << 7) + kk * 64 + ((lane >> 4) << 4)) ^ ((brow & 7) << 4);
      accS[n] = mfma16(aq, *reinterpret_cast<const s8v*>(LK + bad), accS[n]);
      accO[n] = mfma16(aq, *reinterpret_cast<const s8v*>(LS + bad), accO[n]);
    }
  }
  __syncthreads();   // all LQ reads done before P overwrites it
#pragma unroll
  for (int n = 0; n < 4; ++n)
#pragma unroll
    for (int r = 0; r < 4; ++r) {
      int i = wave * 16 + ((lane >> 4) << 2) + r;
      int j = n * 16 + (lane & 15);
      float v = (j <= i) ? accS[n][r] : 0.f;
      int ad = ((i << 7) + (j << 1)) ^ ((i & 7) << 4);
      *reinterpret_cast<short*>(LQ + ad) = (short)f2b(v);
    }
  __syncthreads();
#pragma unroll
  for (int kk = 0; kk < 2; ++kk) {
    int arow = wave * 16 + (lane & 15);
    int aad = ((arow << 7) + kk * 64 + ((lane >> 4) << 4)) ^ ((arow & 7) << 4);
    s8v ap = *reinterpret_cast<const s8v*>(LQ + aad);
#pragma unroll
    for (int n = 0; n < 4; ++n) {
      int brow = n * 16 + (lane & 15);
      int bad = ((brow << 7) + kk * 64 + ((lane >> 4) << 4)) ^ ((brow & 7) << 4);
      accO[n] = mfma16(ap, *reinterpret_cast<const s8v*>(LV + bad), accO[n]);
    }
  }
  int b = bh >> 3, h = bh & 7;
#pragma unroll
  for (int n = 0; n < 4; ++n)
#pragma unroll
    for (int r = 0; r < 4; ++r) {
      int i = wave * 16 + ((lane >> 4) << 2) + r;
      int col = h * 64 + n * 16 + (lane & 15);
      size_t row = (size_t)b * 2048 + chunk * 64 + i;
      aout[row * 512 + col] = (short)f2b(accO[n][r]);
    }
}

// ---------------- stage: gemm<1> (output projection) -------------------------
__device__ __forceinline__ void st_gemm1(int vid, int tid, char* arena,
    const short* __restrict__ aout, const short* __restrict__ woT,
    float* __restrict__ out, const float* __restrict__ b_out) {
  const int lane = tid & 63, wave = tid >> 6;
  int xcd = vid & 7, rq = vid >> 3;
  int bx = rq & 7, by = xcd * 8 + (rq >> 3);       // bijective XCD swizzle
  int m0 = by * 64, n0 = bx * 64;
  f32x4 acc[2][2] = {};
  gemm_core<64, 64, 2, 2>(aout, woT, arena, arena + 8192, m0, n0, tid, acc);
  int wr = (wave >> 1) * 32, wc = (wave & 1) * 32;
#pragma unroll
  for (int m = 0; m < 2; ++m)
#pragma unroll
    for (int n = 0; n < 2; ++n)
#pragma unroll
      for (int r = 0; r < 4; ++r) {
        int row = m0 + wr + m * 16 + ((lane >> 4) << 2) + r;
        int col = n0 + wc + n * 16 + (lane & 15);
        out[(size_t)row * 512 + col] = acc[m][n][r] + b_out[col];
      }
}

// ---------------- mega kernel (cooperative) ----------------------------------
__global__ __launch_bounds__(256, 2) void mega_k(
    const float* __restrict__ x, const float* __restrict__ gamma,
    const float* __restrict__ w_qkv, const float* __restrict__ b_qkv,
    const float* __restrict__ w_a, const float* __restrict__ b_a,
    const float* __restrict__ w_out, const float* __restrict__ b_out,
    float* __restrict__ out,
    short* __restrict__ xnb, short* __restrict__ wT, short* __restrict__ woT,
    short* __restrict__ qkvb, float* __restrict__ araw, float* __restrict__ csum,
    short* __restrict__ q2, short* __restrict__ k2, short* __restrict__ vT,
    short* __restrict__ Sbuf, short* __restrict__ Spre, short* __restrict__ aout) {
  __shared__ __align__(16) char arena[32768];
  cg::grid_group grid = cg::this_grid();
  const int bid = blockIdx.x, tid = threadIdx.x;

  for (int u = bid; u < 2304; u += 512)
    st_prep(u, tid, arena, x, gamma, xnb, w_qkv, w_a, w_out, wT, woT);
  __threadfence(); grid.sync();

  st_gemm0(bid, tid, arena, xnb, wT, qkvb, b_qkv, b_a, araw, csum);
  __threadfence(); grid.sync();

  st_scan2(bid, tid, arena, qkvb, araw, csum, q2, k2, vT, Sbuf);
  __threadfence(); grid.sync();

  if (bid < 256) st_sprefix(bid, tid, Sbuf, Spre);
  __threadfence(); grid.sync();

  st_attnk(bid, tid, arena, q2, k2, vT, Spre, aout);
  __threadfence(); grid.sync();

  st_gemm1(bid, tid, arena, aout, woT, out, b_out);
}

// ---------------- fallback wrappers (identical math, 6 launches) -------------
__global__ __launch_bounds__(256) void prep_k(const float* x, const float* gamma,
    short* xnb, const float* w_qkv, const float* w_a, const float* w_out,
    short* wT, short* woT) {
  __shared__ __align__(16) char arena[4224];
  st_prep(blockIdx.x, threadIdx.x, arena, x, gamma, xnb, w_qkv, w_a, w_out, wT, woT);
}
__global__ __launch_bounds__(256) void gemm0_k(const short* xnb, const short* wT,
    short* qkvb, const float* b_qkv, const float* b_a, float* araw, float* csum) {
  __shared__ __align__(16) char arena[32768];
  st_gemm0(blockIdx.x, threadIdx.x, arena, xnb, wT, qkvb, b_qkv, b_a, araw, csum);
}
__global__ __launch_bounds__(256) void scan2_k(const short* qkvb, const float* araw,
    const float* csum, short* q2, short* k2, short* vT, short* Sbuf) {
  __shared__ __align__(16) char arena[32768];
  st_scan2(blockIdx.x, threadIdx.x, arena, qkvb, araw, csum, q2, k2, vT, Sbuf);
}
__global__ __launch_bounds__(256) void sprefix_k(const short* Sbuf, short* Spre) {
  st_sprefix(blockIdx.x, threadIdx.x, Sbuf, Spre);
}
__global__ __launch_bounds__(256) void attnk_k(const short* q2, const short* k2,
    const short* vT, const short* Spre, short* aout) {
  __shared__ __align__(16) char arena[32768];
  st_attnk(blockIdx.x, threadIdx.x, arena, q2, k2, vT, Spre, aout);
}
__global__ __launch_bounds__(256) void gemm1_k(const short* aout, const short* woT,
    float* out, const float* b_out) {
  __shared__ __align__(16) char arena[16384];
  st_gemm1(blockIdx.x, threadIdx.x, arena, aout, woT, out, b_out);
}

// ---------------------------------------------------------------------------
extern "C" void kernel_launch(void* const* d_in, const int* in_sizes, int n_in,
                              void* d_out, int out_size, void* d_ws, size_t ws_size,
                              hipStream_t stream) {
  const float* x     = (const float*)d_in[0];
  const float* gamma = (const float*)d_in[1];
  const float* w_qkv = (const float*)d_in[2];
  const float* b_qkv = (const float*)d_in[3];
  const float* w_a   = (const float*)d_in[4];
  const float* b_a   = (const float*)d_in[5];
  const float* w_out = (const float*)d_in[6];
  const float* b_out = (const float*)d_in[7];
  float* out = (float*)d_out;
  char* ws = (char*)d_ws;

  const size_t MB = 1u << 20;
  short* xnb  = (short*)(ws);                 // 4 MiB   [4096][512] bf16
  short* wT   = (short*)(ws + 4  * MB);       // 2 MiB   [2048][512] bf16
  short* woT  = (short*)(ws + 6  * MB);       // 0.5 MiB [512][512]  bf16
  short* qkvb = (short*)(ws + 7  * MB);       // 12 MiB  [3][2][8][2048][64] bf16
  float* araw = (float*)(ws + 19 * MB);       // 8 MiB   [16][2048][64] f32
  float* csum = (float*)(ws + 27 * MB);       // 128 KiB [16][32][64] f32
  short* q2   = (short*)(ws + 28 * MB);       // 4 MiB   [16][2048][64] bf16
  short* k2   = (short*)(ws + 32 * MB);       // 4 MiB
  short* vT   = (short*)(ws + 36 * MB);       // 4 MiB   [16][64][2048]
  short* Sbuf = (short*)(ws + 40 * MB);       // 4 MiB   [16][32][64][64] bf16
  short* Spre = (short*)(ws + 44 * MB);       // 4 MiB
  short* aout = (short*)(ws + 48 * MB);       // 4 MiB   [4096][512] bf16

  // capture-safe, deterministic host queries
  int dev = 0; (void)hipGetDevice(&dev);
  int coop = 0;
  (void)hipDeviceGetAttribute(&coop, hipDeviceAttributeCooperativeLaunch, dev);
  int nb = 0;
  (void)hipOccupancyMaxActiveBlocksPerMultiprocessor(&nb, mega_k, 256, 0);

  hipError_t err = hipErrorUnknown;
  if (coop && nb >= 2) {
    void* args[] = {&x, &gamma, &w_qkv, &b_qkv, &w_a, &b_a, &w_out, &b_out,
                    &out, &xnb, &wT, &woT, &qkvb, &araw, &csum,
                    &q2, &k2, &vT, &Sbuf, &Spre, &aout};
    err = hipLaunchCooperativeKernel((void*)mega_k, dim3(512), dim3(256), args, 0, stream);
  }
  if (err != hipSuccess) {
    prep_k   <<<2304, 256, 0, stream>>>(x, gamma, xnb, w_qkv, w_a, w_out, wT, woT);
    gemm0_k  <<<512,  256, 0, stream>>>(xnb, wT, qkvb, b_qkv, b_a, araw, csum);
    scan2_k  <<<512,  256, 0, stream>>>(qkvb, araw, csum, q2, k2, vT, Sbuf);
    sprefix_k<<<256,  256, 0, stream>>>(Sbuf, Spre);
    attnk_k  <<<512,  256, 0, stream>>>(q2, k2, vT, Spre, aout);
    gemm1_k  <<<512,  256, 0, stream>>>(aout, woT, out, b_out);
  }
}

// Round 9
// 70.956 us; speedup vs baseline: 1.0026x; 1.0004x over previous
//
#include <hip/hip_runtime.h>
#include <hip/hip_cooperative_groups.h>

// ---------------------------------------------------------------------------
// CausalFullAttention (decay-gated causal linear attention), MI355X gfx950
// b=2, n=2048, DIM=512, HEADS=8, DIM_HEAD=64
// R9: cooperative mega-kernel exploiting LDS/register persistence across
//     grid.sync: scan2+kstate+attnk merged (q2/k2/vT globals eliminated,
//     ~28MB HBM traffic removed). prep/gemm0/gemm1 unchanged.
//     Proven 6-kernel fallback retained (gated + error-checked).
// ---------------------------------------------------------------------------

namespace cg = cooperative_groups;

using s8v   = __attribute__((ext_vector_type(8))) short;   // 8 x bf16 bits
using f32x4 = __attribute__((ext_vector_type(4))) float;

__device__ __forceinline__ unsigned short f2b(float f) {
  unsigned int u = __builtin_bit_cast(unsigned int, f);
  u += 0x7FFFu + ((u >> 16) & 1u);          // RNE
  return (unsigned short)(u >> 16);
}
__device__ __forceinline__ float b2f(unsigned short b) {
  unsigned int u = ((unsigned int)b) << 16;
  return __builtin_bit_cast(float, u);
}
__device__ __forceinline__ f32x4 mfma16(s8v a, s8v b, f32x4 c) {
  return __builtin_amdgcn_mfma_f32_16x16x32_bf16(a, b, c, 0, 0, 0);
}
__device__ __forceinline__ void gload16(const void* g, void* l) {
  __builtin_amdgcn_global_load_lds(
      (const __attribute__((address_space(1))) void*)g,
      (__attribute__((address_space(3))) void*)l, 16, 0, 0);
}

// ---------------- stage: prep (rmsnorm u<1024 | wtrans u>=1024) --------------
__device__ __forceinline__ void st_prep(int u, int tid, char* arena,
    const float* __restrict__ x, const float* __restrict__ gamma,
    short* __restrict__ xnb,
    const float* __restrict__ w_qkv, const float* __restrict__ w_a,
    const float* __restrict__ w_out,
    short* __restrict__ wT, short* __restrict__ woT) {
  int lane = tid & 63, wave = tid >> 6;
  if (u < 1024) {
    int row = u * 4 + wave;
    const float4* xp = reinterpret_cast<const float4*>(x + (size_t)row * 512 + lane * 8);
    float4 v0 = xp[0], v1 = xp[1];
    float ss = v0.x*v0.x + v0.y*v0.y + v0.z*v0.z + v0.w*v0.w
             + v1.x*v1.x + v1.y*v1.y + v1.z*v1.z + v1.w*v1.w;
#pragma unroll
    for (int off = 32; off > 0; off >>= 1) ss += __shfl_xor(ss, off, 64);
    float s = 22.627416997969522f / fmaxf(sqrtf(ss), 1e-12f);
    const float* g = gamma + lane * 8;
    float vals[8] = {v0.x, v0.y, v0.z, v0.w, v1.x, v1.y, v1.z, v1.w};
    s8v o;
#pragma unroll
    for (int j = 0; j < 8; ++j) o[j] = (short)f2b(vals[j] * s * g[j]);
    *reinterpret_cast<s8v*>(xnb + (size_t)row * 512 + lane * 8) = o;
  } else {
    float (*t)[33] = reinterpret_cast<float (*)[33]>(arena);
    int id = u - 1024;
    int bx = id % 80, k0 = (id / 80) * 32;
    const float* src; short* dst; int N, n0;
    if (bx < 48)      { src = w_qkv; dst = wT;                      N = 1536; n0 = bx * 32; }
    else if (bx < 64) { src = w_a;   dst = wT + (size_t)1536 * 512; N = 512;  n0 = (bx - 48) * 32; }
    else              { src = w_out; dst = woT;                     N = 512;  n0 = (bx - 64) * 32; }
    int tx = tid & 31, ty = tid >> 5;
    __syncthreads();   // prior arena use complete
#pragma unroll
    for (int i = 0; i < 4; ++i)
      t[ty + 8 * i][tx] = src[(size_t)(k0 + ty + 8 * i) * N + n0 + tx];
    __syncthreads();
#pragma unroll
    for (int i = 0; i < 4; ++i)
      dst[(size_t)(n0 + ty + 8 * i) * 512 + k0 + tx] = (short)f2b(t[tx][ty + 8 * i]);
  }
}

// ---------------- shared single-buffered GEMM core (m97 structure) -----------
template <int BM, int BN, int FM, int FN>
__device__ __forceinline__ void gemm_core(const short* __restrict__ A,
                                          const short* __restrict__ Bm,
                                          char* LA, char* LB,
                                          int m0, int n0, int tid,
                                          f32x4 (&acc)[FM][FN]) {
  const int lane = tid & 63, wave = tid >> 6;
  const int wr = (wave >> 1) * (BM / 2), wc = (wave & 1) * (BN / 2);
#pragma unroll 1
  for (int t = 0; t < 8; ++t) {            // K = 512, BK = 64
    const int k0 = t * 64;
#pragma unroll
    for (int r = 0; r < BM / 32; ++r) {
      int o = r * 4096 + tid * 16;
      int row = o >> 7;
      int ce = (((o & 127) ^ ((row & 7) << 4)) >> 1);   // pre-swizzled src col
      gload16(A + (size_t)(m0 + row) * 512 + k0 + ce, LA + o);
    }
#pragma unroll
    for (int r = 0; r < BN / 32; ++r) {
      int o = r * 4096 + tid * 16;
      int row = o >> 7;
      int ce = (((o & 127) ^ ((row & 7) << 4)) >> 1);
      gload16(Bm + (size_t)(n0 + row) * 512 + k0 + ce, LB + o);
    }
    __syncthreads();                       // tile ready (vmcnt drained)
#pragma unroll
    for (int kk = 0; kk < 2; ++kk) {
      s8v af[FM], bf[FN];
#pragma unroll
      for (int m = 0; m < FM; ++m) {
        int row = wr + m * 16 + (lane & 15);
        int ad = ((row << 7) + kk * 64 + ((lane >> 4) << 4)) ^ ((row & 7) << 4);
        af[m] = *reinterpret_cast<const s8v*>(LA + ad);
      }
#pragma unroll
      for (int n = 0; n < FN; ++n) {
        int row = wc + n * 16 + (lane & 15);
        int ad = ((row << 7) + kk * 64 + ((lane >> 4) << 4)) ^ ((row & 7) << 4);
        bf[n] = *reinterpret_cast<const s8v*>(LB + ad);
      }
#pragma unroll
      for (int m = 0; m < FM; ++m)
#pragma unroll
        for (int n = 0; n < FN; ++n)
          acc[m][n] = mfma16(af[m], bf[n], acc[m][n]);
    }
    if (t + 1 < 8) __syncthreads();        // reads done before next overwrite
  }
}

// ---------------- stage: gemm<0> + qkv/gate epilogue -------------------------
__device__ __forceinline__ void st_gemm0(int vid, int tid, char* arena,
    const short* __restrict__ xnb, const short* __restrict__ wT,
    short* __restrict__ qkvb, const float* __restrict__ b_qkv,
    const float* __restrict__ b_a, float* __restrict__ araw,
    float* __restrict__ csum) {
  const int lane = tid & 63, wave = tid >> 6;
  int xcd = vid & 7, rq = vid >> 3;
  int bx = rq & 15, by = xcd * 4 + (rq >> 4);      // bijective XCD swizzle
  int m0 = by * 128, n0 = bx * 128;
  f32x4 acc[4][4] = {};
  gemm_core<128, 128, 4, 4>(xnb, wT, arena, arena + 16384, m0, n0, tid, acc);
  int wr = (wave >> 1) * 64, wc = (wave & 1) * 64;
  if (n0 < 1536) {
#pragma unroll
    for (int m = 0; m < 4; ++m)
#pragma unroll
      for (int n = 0; n < 4; ++n)
#pragma unroll
        for (int r = 0; r < 4; ++r) {
          int row = m0 + wr + m * 16 + ((lane >> 4) << 2) + r;
          int col = n0 + wc + n * 16 + (lane & 15);
          float v = acc[m][n][r] + b_qkv[col];
          int w = col >> 9, h = (col >> 6) & 7, d = col & 63;
          int b = row >> 11, nn = row & 2047;
          qkvb[((((size_t)(w * 2 + b)) * 8 + h) * 2048 + nn) * 64 + d] = (short)f2b(v);
        }
  } else {
    float cs[4] = {};
    int b = m0 >> 11;
#pragma unroll
    for (int m = 0; m < 4; ++m)
#pragma unroll
      for (int n = 0; n < 4; ++n)
#pragma unroll
        for (int r = 0; r < 4; ++r) {
          int row = m0 + wr + m * 16 + ((lane >> 4) << 2) + r;
          int gc = n0 + wc + n * 16 + (lane & 15) - 1536;
          int h = gc >> 6, d = gc & 63, nn = row & 2047;
          float xv = acc[m][n][r] + b_a[gc];
          araw[((size_t)(b * 8 + h) * 2048 + nn) * 64 + d] = xv;
          float a = 1.f / (1.f + expf(-xv));
          a = fminf(fmaxf(a, 1e-10f), 1.f);
          cs[n] += logf(a);
        }
#pragma unroll
    for (int n = 0; n < 4; ++n) {
      cs[n] += __shfl_xor(cs[n], 16, 64);
      cs[n] += __shfl_xor(cs[n], 32, 64);
    }
    int nsel = lane >> 4;
    float v = (nsel == 0) ? cs[0] : (nsel == 1) ? cs[1] : (nsel == 2) ? cs[2] : cs[3];
    int col = wc + nsel * 16 + (lane & 15);
    int gc = n0 + col - 1536;
    int h = gc >> 6, d = gc & 63;
    int chunkg = ((m0 & 2047) >> 6) + (wave >> 1);
    csum[(((size_t)(b * 8 + h)) * 32 + chunkg) * 64 + d] = v;
  }
}

// ---------------- fallback stages (R8 path: q2/k2/vT materialized) -----------
__device__ __forceinline__ void st_scan2(int vid, int tid, char* arena,
    const short* __restrict__ qkvb, const float* __restrict__ araw,
    const float* __restrict__ csum, short* __restrict__ q2,
    short* __restrict__ k2, short* __restrict__ vT, short* __restrict__ Sbuf) {
  int chunk = vid & 31, bh = vid >> 5;
  int lane = tid & 63, wave = tid >> 6, d = lane;
  short (*kL)[64] = reinterpret_cast<short (*)[64]>(arena);
  short (*vL)[64] = reinterpret_cast<short (*)[64]>(arena + 8192);
  char* kT  = arena + 16384;
  char* vTl = arena + 24576;
  float (*wsum)[64] = reinterpret_cast<float (*)[64]>(arena + 16384);
  float pre = 0.f;
  for (int c = 0; c < chunk; ++c) pre += csum[((size_t)bh * 32 + c) * 64 + d];
  const float* ap = araw + ((size_t)bh * 2048 + chunk * 64 + wave * 16) * 64 + d;
  float la[16]; float run = 0.f;
#pragma unroll
  for (int rr = 0; rr < 16; ++rr) {
    float xv = ap[rr * 64];
    float a = 1.f / (1.f + expf(-xv));
    a = fminf(fmaxf(a, 1e-10f), 1.f);
    run += logf(a);
    la[rr] = run;
  }
  wsum[wave][d] = run;
  __syncthreads();
#pragma unroll
  for (int w = 0; w < 3; ++w) if (w < wave) pre += wsum[w][d];
  const size_t WS = (size_t)2 * 8 * 2048 * 64;
  size_t base = ((size_t)bh * 2048 + chunk * 64 + wave * 16) * 64 + d;
#pragma unroll 4
  for (int rr = 0; rr < 16; ++rr) {
    int r = wave * 16 + rr;
    float g = expf(pre + la[rr]);
    float gi = 1.f / fmaxf(g, 1e-8f);
    float qv = b2f((unsigned short)qkvb[base + rr * 64]);
    float kv = b2f((unsigned short)qkvb[base + WS + rr * 64]);
    short vb = qkvb[base + 2 * WS + rr * 64];
    q2[base + rr * 64] = (short)f2b(qv * 0.125f * g);
    unsigned short kb = f2b(kv * gi);
    k2[base + rr * 64] = (short)kb;
    kL[r][d] = (short)kb;
    vL[r][d] = vb;
  }
  __syncthreads();
  short* vTrow = vT + ((size_t)bh * 64 + d) * 2048 + chunk * 64;
#pragma unroll
  for (int gg = 0; gg < 2; ++gg) {
    int g8 = wave + gg * 4;
    s8v pk, pv;
#pragma unroll
    for (int j = 0; j < 8; ++j) { pk[j] = kL[g8 * 8 + j][d]; pv[j] = vL[g8 * 8 + j][d]; }
    *reinterpret_cast<s8v*>(vTrow + g8 * 8) = pv;
    int ad = ((d << 7) + g8 * 16) ^ ((d & 7) << 4);
    *reinterpret_cast<s8v*>(kT  + ad) = pk;
    *reinterpret_cast<s8v*>(vTl + ad) = pv;
  }
  __syncthreads();
  f32x4 acc[4] = {};
#pragma unroll
  for (int kk = 0; kk < 2; ++kk) {
    int arow = wave * 16 + (lane & 15);
    int aad = ((arow << 7) + kk * 64 + ((lane >> 4) << 4)) ^ ((arow & 7) << 4);
    s8v av = *reinterpret_cast<const s8v*>(vTl + aad);
#pragma unroll
    for (int n = 0; n < 4; ++n) {
      int brow = n * 16 + (lane & 15);
      int bad = ((brow << 7) + kk * 64 + ((lane >> 4) << 4)) ^ ((brow & 7) << 4);
      acc[n] = mfma16(av, *reinterpret_cast<const s8v*>(kT + bad), acc[n]);
    }
  }
  short* Sp = Sbuf + ((size_t)bh * 32 + chunk) * 4096;
#pragma unroll
  for (int n = 0; n < 4; ++n)
#pragma unroll
    for (int r = 0; r < 4; ++r)
      Sp[(wave * 16 + ((lane >> 4) << 2) + r) * 64 + n * 16 + (lane & 15)] = (short)f2b(acc[n][r]);
}

__device__ __forceinline__ void st_sprefix(int vid, int tid,
    const short* __restrict__ Sbuf, short* __restrict__ Spre) {
  int bh = vid >> 4;
  int e = ((vid & 15) << 8) + tid;
  size_t base = (size_t)bh * 32 * 4096 + e;
  float acc = 0.f;
  for (int c = 0; c < 32; ++c) {
    Spre[base + (size_t)c * 4096] = (short)f2b(acc);
    acc += b2f((unsigned short)Sbuf[base + (size_t)c * 4096]);
  }
}

__device__ __forceinline__ void st_attnk(int vid, int tid, char* arena,
    const short* __restrict__ q2, const short* __restrict__ k2,
    const short* __restrict__ vT, const short* __restrict__ Spre,
    short* __restrict__ aout) {
  int chunk = vid & 31, bh = vid >> 5;
  int lane = tid & 63, wave = tid >> 6;
  char* LQ = arena;              // later reused for P
  char* LK = arena + 8192;
  char* LV = arena + 16384;
  char* LS = arena + 24576;
#pragma unroll
  for (int rr = 0; rr < 2; ++rr) {
    int o = rr * 4096 + tid * 16;
    int row = o >> 7;
    int ce = (((o & 127) ^ ((row & 7) << 4)) >> 1);
    gload16(q2   + ((size_t)bh * 2048 + chunk * 64 + row) * 64 + ce, LQ + o);
    gload16(k2   + ((size_t)bh * 2048 + chunk * 64 + row) * 64 + ce, LK + o);
    gload16(vT   + ((size_t)bh * 64 + row) * 2048 + chunk * 64 + ce, LV + o);
    gload16(Spre + (((size_t)bh * 32 + chunk) * 64 + row) * 64 + ce, LS + o);
  }
  __syncthreads();
  f32x4 accS[4] = {}, accO[4] = {};
#pragma unroll
  for (int kk = 0; kk < 2; ++kk) {
    int arow = wave * 16 + (lane & 15);
    int aad = ((arow << 7) + kk * 64 + ((lane >> 4) << 4)) ^ ((arow & 7) << 4);
    s8v aq = *reinterpret_cast<const s8v*>(LQ + aad);
#pragma unroll
    for (int n = 0; n < 4; ++n) {
      int brow = n * 16 + (lane & 15);
      int bad = ((brow << 7) + kk * 64 + ((lane >> 4) << 4)) ^ ((brow & 7) << 4);
      accS[n] = mfma16(aq, *reinterpret_cast<const s8v*>(LK + bad), accS[n]);
      accO[n] = mfma16(aq, *reinterpret_cast<const s8v*>(LS + bad), accO[n]);
    }
  }
  __syncthreads();
#pragma unroll
  for (int n = 0; n < 4; ++n)
#pragma unroll
    for (int r = 0; r < 4; ++r) {
      int i = wave * 16 + ((lane >> 4) << 2) + r;
      int j = n * 16 + (lane & 15);
      float v = (j <= i) ? accS[n][r] : 0.f;
      int ad = ((i << 7) + (j << 1)) ^ ((i & 7) << 4);
      *reinterpret_cast<short*>(LQ + ad) = (short)f2b(v);
    }
  __syncthreads();
#pragma unroll
  for (int kk = 0; kk < 2; ++kk) {
    int arow = wave * 16 + (lane & 15);
    int aad = ((arow << 7) + kk * 64 + ((lane >> 4) << 4)) ^ ((arow & 7) << 4);
    s8v ap = *reinterpret_cast<const s8v*>(LQ + aad);
#pragma unroll
    for (int n = 0; n < 4; ++n) {
      int brow = n * 16 + (lane & 15);
      int bad = ((brow << 7) + kk * 64 + ((lane >> 4) << 4)) ^ ((brow & 7) << 4);
      accO[n] = mfma16(ap, *reinterpret_cast<const s8v*>(LV + bad), accO[n]);
    }
  }
  int b = bh >> 3, h = bh & 7;
#pragma unroll
  for (int n = 0; n < 4; ++n)
#pragma unroll
    for (int r = 0; r < 4; ++r) {
      int i = wave * 16 + ((lane >> 4) << 2) + r;
      int col = h * 64 + n * 16 + (lane & 15);
      size_t row = (size_t)b * 2048 + chunk * 64 + i;
      aout[row * 512 + col] = (short)f2b(accO[n][r]);
    }
}

// ---------------- stage: gemm<1> (output projection) -------------------------
__device__ __forceinline__ void st_gemm1(int vid, int tid, char* arena,
    const short* __restrict__ aout, const short* __restrict__ woT,
    float* __restrict__ out, const float* __restrict__ b_out) {
  const int lane = tid & 63, wave = tid >> 6;
  int xcd = vid & 7, rq = vid >> 3;
  int bx = rq & 7, by = xcd * 8 + (rq >> 3);       // bijective XCD swizzle
  int m0 = by * 64, n0 = bx * 64;
  f32x4 acc[2][2] = {};
  gemm_core<64, 64, 2, 2>(aout, woT, arena, arena + 8192, m0, n0, tid, acc);
  int wr = (wave >> 1) * 32, wc = (wave & 1) * 32;
#pragma unroll
  for (int m = 0; m < 2; ++m)
#pragma unroll
    for (int n = 0; n < 2; ++n)
#pragma unroll
      for (int r = 0; r < 4; ++r) {
        int row = m0 + wr + m * 16 + ((lane >> 4) << 2) + r;
        int col = n0 + wc + n * 16 + (lane & 15);
        out[(size_t)row * 512 + col] = acc[m][n][r] + b_out[col];
      }
}

// ---------------- mega kernel (cooperative, persistent-LDS merge) ------------
__global__ __launch_bounds__(256, 2) void mega_k(
    const float* __restrict__ x, const float* __restrict__ gamma,
    const float* __restrict__ w_qkv, const float* __restrict__ b_qkv,
    const float* __restrict__ w_a, const float* __restrict__ b_a,
    const float* __restrict__ w_out, const float* __restrict__ b_out,
    float* __restrict__ out,
    short* __restrict__ xnb, short* __restrict__ wT, short* __restrict__ woT,
    short* __restrict__ qkvb, float* __restrict__ araw, float* __restrict__ csum,
    short* __restrict__ Sbuf, short* __restrict__ Spre, short* __restrict__ aout) {
  __shared__ __align__(16) char arena[32768];
  cg::grid_group grid = cg::this_grid();
  const int bid = blockIdx.x, tid = threadIdx.x;
  const int lane = tid & 63, wave = tid >> 6;

  // ---- S1: prep ----
  for (int u = bid; u < 2304; u += 512)
    st_prep(u, tid, arena, x, gamma, xnb, w_qkv, w_a, w_out, wT, woT);
  __threadfence(); grid.sync();

  // ---- S2: gemm0 ----
  st_gemm0(bid, tid, arena, xnb, wT, qkvb, b_qkv, b_a, araw, csum);
  __threadfence(); grid.sync();

  // ---- S3: gates -> LDS (qL,kR,kT,vTl) + kstate + local causal attention ---
  const int chunk = bid & 31, bh = bid >> 5;
  const int d = lane;
  char* qL  = arena;            // q2 row-major swz   [persists to S5]
  char* kR  = arena + 8192;     // k2 row-major swz   [S5 reuses for Spre]
  char* kT  = arena + 16384;    // k2^T swz           [reused for P]
  char* vTl = arena + 24576;    // v^T swz
  f32x4 accO[4] = {};
  {
    float (*wsum)[64] = reinterpret_cast<float (*)[64]>(kR);  // pre-gate scratch
    float pre = 0.f;
    for (int c = 0; c < chunk; ++c) pre += csum[((size_t)bh * 32 + c) * 64 + d];
    const float* ap = araw + ((size_t)bh * 2048 + chunk * 64 + wave * 16) * 64 + d;
    float la[16]; float run = 0.f;
#pragma unroll
    for (int rr = 0; rr < 16; ++rr) {
      float xv = ap[rr * 64];
      float a = 1.f / (1.f + expf(-xv));
      a = fminf(fmaxf(a, 1e-10f), 1.f);
      run += logf(a);
      la[rr] = run;
    }
    wsum[wave][d] = run;
    __syncthreads();
#pragma unroll
    for (int w = 0; w < 3; ++w) if (w < wave) pre += wsum[w][d];
    __syncthreads();           // wsum reads done before kR is overwritten
    const size_t WS = (size_t)2 * 8 * 2048 * 64;
    size_t base = ((size_t)bh * 2048 + chunk * 64 + wave * 16) * 64 + d;
#pragma unroll 4
    for (int rr = 0; rr < 16; ++rr) {
      int r = wave * 16 + rr;
      float g = expf(pre + la[rr]);            // a_cum
      float gi = 1.f / fmaxf(g, 1e-8f);        // a_cum_inv
      float qv = b2f((unsigned short)qkvb[base + rr * 64]);
      float kv = b2f((unsigned short)qkvb[base + WS + rr * 64]);
      short vb = qkvb[base + 2 * WS + rr * 64];
      unsigned short qb = f2b(qv * 0.125f * g);   // SCALE = 64^-0.5
      unsigned short kb = f2b(kv * gi);
      // row-major swz writes (row uniform per wave-iteration)
      int adr = ((r << 7) + (d << 1)) ^ ((r & 7) << 4);
      *reinterpret_cast<short*>(qL + adr) = (short)qb;
      *reinterpret_cast<short*>(kR + adr) = (short)kb;
      // transposed swz writes (dest row = d, position = r)
      int adt = ((d << 7) + (r << 1)) ^ ((d & 7) << 4);
      *reinterpret_cast<short*>(kT  + adt) = (short)kb;
      *reinterpret_cast<short*>(vTl + adt) = vb;
    }
    __syncthreads();
    // kstate: S^T[dd][d'] = sum_j v[j][dd] k2[j][d']
    f32x4 sacc[4] = {};
#pragma unroll
    for (int kk = 0; kk < 2; ++kk) {
      int arow = wave * 16 + (lane & 15);
      int aad = ((arow << 7) + kk * 64 + ((lane >> 4) << 4)) ^ ((arow & 7) << 4);
      s8v av = *reinterpret_cast<const s8v*>(vTl + aad);
#pragma unroll
      for (int n = 0; n < 4; ++n) {
        int brow = n * 16 + (lane & 15);
        int bad = ((brow << 7) + kk * 64 + ((lane >> 4) << 4)) ^ ((brow & 7) << 4);
        sacc[n] = mfma16(av, *reinterpret_cast<const s8v*>(kT + bad), sacc[n]);
      }
    }
    short* Sp = Sbuf + ((size_t)bh * 32 + chunk) * 4096;
#pragma unroll
    for (int n = 0; n < 4; ++n)
#pragma unroll
      for (int r = 0; r < 4; ++r)
        Sp[(wave * 16 + ((lane >> 4) << 2) + r) * 64 + n * 16 + (lane & 15)] = (short)f2b(sacc[n][r]);
    // scores: sim[i][j] = q2[i]·k2[j]
    f32x4 accS[4] = {};
#pragma unroll
    for (int kk = 0; kk < 2; ++kk) {
      int arow = wave * 16 + (lane & 15);
      int aad = ((arow << 7) + kk * 64 + ((lane >> 4) << 4)) ^ ((arow & 7) << 4);
      s8v aq = *reinterpret_cast<const s8v*>(qL + aad);
#pragma unroll
      for (int n = 0; n < 4; ++n) {
        int brow = n * 16 + (lane & 15);
        int bad = ((brow << 7) + kk * 64 + ((lane >> 4) << 4)) ^ ((brow & 7) << 4);
        accS[n] = mfma16(aq, *reinterpret_cast<const s8v*>(kR + bad), accS[n]);
      }
    }
    __syncthreads();           // kT reads (kstate) done before P overwrites
#pragma unroll
    for (int n = 0; n < 4; ++n)
#pragma unroll
      for (int r = 0; r < 4; ++r) {
        int i = wave * 16 + ((lane >> 4) << 2) + r;
        int j = n * 16 + (lane & 15);
        float v = (j <= i) ? accS[n][r] : 0.f;
        int ad = ((i << 7) + (j << 1)) ^ ((i & 7) << 4);
        *reinterpret_cast<short*>(kT + ad) = (short)f2b(v);
      }
    __syncthreads();
    // PV: accO[i][d'] = sum_j P[i][j] v[j][d']
#pragma unroll
    for (int kk = 0; kk < 2; ++kk) {
      int arow = wave * 16 + (lane & 15);
      int aad = ((arow << 7) + kk * 64 + ((lane >> 4) << 4)) ^ ((arow & 7) << 4);
      s8v ap = *reinterpret_cast<const s8v*>(kT + aad);
#pragma unroll
      for (int n = 0; n < 4; ++n) {
        int brow = n * 16 + (lane & 15);
        int bad = ((brow << 7) + kk * 64 + ((lane >> 4) << 4)) ^ ((brow & 7) << 4);
        accO[n] = mfma16(ap, *reinterpret_cast<const s8v*>(vTl + bad), accO[n]);
      }
    }
  }
  __threadfence(); grid.sync();

  // ---- S4: sprefix (qL + accO persist in all blocks) ----
  if (bid < 256) st_sprefix(bid, tid, Sbuf, Spre);
  __threadfence(); grid.sync();

  // ---- S5: accO += q2 @ Spre; write aout ----
  {
    char* LS = kR;             // reuse kR area (linear dest for gload16)
#pragma unroll
    for (int rr = 0; rr < 2; ++rr) {
      int o = rr * 4096 + tid * 16;
      int row = o >> 7;
      int ce = (((o & 127) ^ ((row & 7) << 4)) >> 1);
      gload16(Spre + (((size_t)bh * 32 + chunk) * 64 + row) * 64 + ce, LS + o);
    }
    __syncthreads();
#pragma unroll
    for (int kk = 0; kk < 2; ++kk) {
      int arow = wave * 16 + (lane & 15);
      int aad = ((arow << 7) + kk * 64 + ((lane >> 4) << 4)) ^ ((arow & 7) << 4);
      s8v aq = *reinterpret_cast<const s8v*>(qL + aad);
#pragma unroll
      for (int n = 0; n < 4; ++n) {
        int brow = n * 16 + (lane & 15);
        int bad = ((brow << 7) + kk * 64 + ((lane >> 4) << 4)) ^ ((brow & 7) << 4);
        accO[n] = mfma16(aq, *reinterpret_cast<const s8v*>(LS + bad), accO[n]);
      }
    }
    int b = bh >> 3, h = bh & 7;
#pragma unroll
    for (int n = 0; n < 4; ++n)
#pragma unroll
      for (int r = 0; r < 4; ++r) {
        int i = wave * 16 + ((lane >> 4) << 2) + r;
        int col = h * 64 + n * 16 + (lane & 15);
        size_t row = (size_t)b * 2048 + chunk * 64 + i;
        aout[row * 512 + col] = (short)f2b(accO[n][r]);
      }
  }
  __threadfence(); grid.sync();

  // ---- S6: gemm1 ----
  st_gemm1(bid, tid, arena, aout, woT, out, b_out);
}

// ---------------- fallback wrappers (R8 proven path) -------------------------
__global__ __launch_bounds__(256) void prep_k(const float* x, const float* gamma,
    short* xnb, const float* w_qkv, const float* w_a, const float* w_out,
    short* wT, short* woT) {
  __shared__ __align__(16) char arena[4224];
  st_prep(blockIdx.x, threadIdx.x, arena, x, gamma, xnb, w_qkv, w_a, w_out, wT, woT);
}
__global__ __launch_bounds__(256) void gemm0_k(const short* xnb, const short* wT,
    short* qkvb, const float* b_qkv, const float* b_a, float* araw, float* csum) {
  __shared__ __align__(16) char arena[32768];
  st_gemm0(blockIdx.x, threadIdx.x, arena, xnb, wT, qkvb, b_qkv, b_a, araw, csum);
}
__global__ __launch_bounds__(256) void scan2_k(const short* qkvb, const float* araw,
    const float* csum, short* q2, short* k2, short* vT, short* Sbuf) {
  __shared__ __align__(16) char arena[32768];
  st_scan2(blockIdx.x, threadIdx.x, arena, qkvb, araw, csum, q2, k2, vT, Sbuf);
}
__global__ __launch_bounds__(256) void sprefix_k(const short* Sbuf, short* Spre) {
  st_sprefix(blockIdx.x, threadIdx.x, Sbuf, Spre);
}
__global__ __launch_bounds__(256) void attnk_k(const short* q2, const short* k2,
    const short* vT, const short* Spre, short* aout) {
  __shared__ __align__(16) char arena[32768];
  st_attnk(blockIdx.x, threadIdx.x, arena, q2, k2, vT, Spre, aout);
}
__global__ __launch_bounds__(256) void gemm1_k(const short* aout, const short* woT,
    float* out, const float* b_out) {
  __shared__ __align__(16) char arena[16384];
  st_gemm1(blockIdx.x, threadIdx.x, arena, aout, woT, out, b_out);
}

// ---------------------------------------------------------------------------
extern "C" void kernel_launch(void* const* d_in, const int* in_sizes, int n_in,
                              void* d_out, int out_size, void* d_ws, size_t ws_size,
                              hipStream_t stream) {
  const float* x     = (const float*)d_in[0];
  const float* gamma = (const float*)d_in[1];
  const float* w_qkv = (const float*)d_in[2];
  const float* b_qkv = (const float*)d_in[3];
  const float* w_a   = (const float*)d_in[4];
  const float* b_a   = (const float*)d_in[5];
  const float* w_out = (const float*)d_in[6];
  const float* b_out = (const float*)d_in[7];
  float* out = (float*)d_out;
  char* ws = (char*)d_ws;

  const size_t MB = 1u << 20;
  short* xnb  = (short*)(ws);                 // 4 MiB   [4096][512] bf16
  short* wT   = (short*)(ws + 4  * MB);       // 2 MiB   [2048][512] bf16
  short* woT  = (short*)(ws + 6  * MB);       // 0.5 MiB [512][512]  bf16
  short* qkvb = (short*)(ws + 7  * MB);       // 12 MiB  [3][2][8][2048][64] bf16
  float* araw = (float*)(ws + 19 * MB);       // 8 MiB   [16][2048][64] f32
  float* csum = (float*)(ws + 27 * MB);       // 128 KiB [16][32][64] f32
  short* Sbuf = (short*)(ws + 28 * MB);       // 4 MiB   [16][32][64][64] bf16
  short* Spre = (short*)(ws + 32 * MB);       // 4 MiB
  short* aout = (short*)(ws + 36 * MB);       // 4 MiB   [4096][512] bf16
  // fallback-only buffers:
  short* q2   = (short*)(ws + 40 * MB);       // 4 MiB
  short* k2   = (short*)(ws + 44 * MB);       // 4 MiB
  short* vT   = (short*)(ws + 48 * MB);       // 4 MiB

  int dev = 0; (void)hipGetDevice(&dev);
  int coop = 0;
  (void)hipDeviceGetAttribute(&coop, hipDeviceAttributeCooperativeLaunch, dev);
  int nb = 0;
  (void)hipOccupancyMaxActiveBlocksPerMultiprocessor(&nb, mega_k, 256, 0);

  hipError_t err = hipErrorUnknown;
  if (coop && nb >= 2) {
    void* args[] = {&x, &gamma, &w_qkv, &b_qkv, &w_a, &b_a, &w_out, &b_out,
                    &out, &xnb, &wT, &woT, &qkvb, &araw, &csum,
                    &Sbuf, &Spre, &aout};
    err = hipLaunchCooperativeKernel((void*)mega_k, dim3(512), dim3(256), args, 0, stream);
  }
  if (err != hipSuccess) {
    prep_k   <<<2304, 256, 0, stream>>>(x, gamma, xnb, w_qkv, w_a, w_out, wT, woT);
    gemm0_k  <<<512,  256, 0, stream>>>(xnb, wT, qkvb, b_qkv, b_a, araw, csum);
    scan2_k  <<<512,  256, 0, stream>>>(qkvb, araw, csum, q2, k2, vT, Sbuf);
    sprefix_k<<<256,  256, 0, stream>>>(Sbuf, Spre);
    attnk_k  <<<512,  256, 0, stream>>>(q2, k2, vT, Spre, aout);
    gemm1_k  <<<512,  256, 0, stream>>>(aout, woT, out, b_out);
  }
}

// Round 10
// 61.737 us; speedup vs baseline: 1.1523x; 1.1493x over previous
//
#include <hip/hip_runtime.h>
#include <hip/hip_cooperative_groups.h>

// ---------------------------------------------------------------------------
// CausalFullAttention (decay-gated causal linear attention), MI355X gfx950
// b=2, n=2048, DIM=512, HEADS=8, DIM_HEAD=64
// R10: == R9 + serial-latency-chain fixes:
//   (1) sprefix: 32 unrolled independent loads, then scan (was 32-dep chain)
//   (2) S3/scan2 csum prefix: fixed-32 masked unroll (was dynamic serial loop)
// Bit-identical arithmetic. Cooperative mega-kernel + 6-kernel fallback.
// ---------------------------------------------------------------------------

namespace cg = cooperative_groups;

using s8v   = __attribute__((ext_vector_type(8))) short;   // 8 x bf16 bits
using f32x4 = __attribute__((ext_vector_type(4))) float;

__device__ __forceinline__ unsigned short f2b(float f) {
  unsigned int u = __builtin_bit_cast(unsigned int, f);
  u += 0x7FFFu + ((u >> 16) & 1u);          // RNE
  return (unsigned short)(u >> 16);
}
__device__ __forceinline__ float b2f(unsigned short b) {
  unsigned int u = ((unsigned int)b) << 16;
  return __builtin_bit_cast(float, u);
}
__device__ __forceinline__ f32x4 mfma16(s8v a, s8v b, f32x4 c) {
  return __builtin_amdgcn_mfma_f32_16x16x32_bf16(a, b, c, 0, 0, 0);
}
__device__ __forceinline__ void gload16(const void* g, void* l) {
  __builtin_amdgcn_global_load_lds(
      (const __attribute__((address_space(1))) void*)g,
      (__attribute__((address_space(3))) void*)l, 16, 0, 0);
}

// ---------------- stage: prep (rmsnorm u<1024 | wtrans u>=1024) --------------
__device__ __forceinline__ void st_prep(int u, int tid, char* arena,
    const float* __restrict__ x, const float* __restrict__ gamma,
    short* __restrict__ xnb,
    const float* __restrict__ w_qkv, const float* __restrict__ w_a,
    const float* __restrict__ w_out,
    short* __restrict__ wT, short* __restrict__ woT) {
  int lane = tid & 63, wave = tid >> 6;
  if (u < 1024) {
    int row = u * 4 + wave;
    const float4* xp = reinterpret_cast<const float4*>(x + (size_t)row * 512 + lane * 8);
    float4 v0 = xp[0], v1 = xp[1];
    float ss = v0.x*v0.x + v0.y*v0.y + v0.z*v0.z + v0.w*v0.w
             + v1.x*v1.x + v1.y*v1.y + v1.z*v1.z + v1.w*v1.w;
#pragma unroll
    for (int off = 32; off > 0; off >>= 1) ss += __shfl_xor(ss, off, 64);
    float s = 22.627416997969522f / fmaxf(sqrtf(ss), 1e-12f);
    const float* g = gamma + lane * 8;
    float vals[8] = {v0.x, v0.y, v0.z, v0.w, v1.x, v1.y, v1.z, v1.w};
    s8v o;
#pragma unroll
    for (int j = 0; j < 8; ++j) o[j] = (short)f2b(vals[j] * s * g[j]);
    *reinterpret_cast<s8v*>(xnb + (size_t)row * 512 + lane * 8) = o;
  } else {
    float (*t)[33] = reinterpret_cast<float (*)[33]>(arena);
    int id = u - 1024;
    int bx = id % 80, k0 = (id / 80) * 32;
    const float* src; short* dst; int N, n0;
    if (bx < 48)      { src = w_qkv; dst = wT;                      N = 1536; n0 = bx * 32; }
    else if (bx < 64) { src = w_a;   dst = wT + (size_t)1536 * 512; N = 512;  n0 = (bx - 48) * 32; }
    else              { src = w_out; dst = woT;                     N = 512;  n0 = (bx - 64) * 32; }
    int tx = tid & 31, ty = tid >> 5;
    __syncthreads();   // prior arena use complete
#pragma unroll
    for (int i = 0; i < 4; ++i)
      t[ty + 8 * i][tx] = src[(size_t)(k0 + ty + 8 * i) * N + n0 + tx];
    __syncthreads();
#pragma unroll
    for (int i = 0; i < 4; ++i)
      dst[(size_t)(n0 + ty + 8 * i) * 512 + k0 + tx] = (short)f2b(t[tx][ty + 8 * i]);
  }
}

// ---------------- shared single-buffered GEMM core (m97 structure) -----------
template <int BM, int BN, int FM, int FN>
__device__ __forceinline__ void gemm_core(const short* __restrict__ A,
                                          const short* __restrict__ Bm,
                                          char* LA, char* LB,
                                          int m0, int n0, int tid,
                                          f32x4 (&acc)[FM][FN]) {
  const int lane = tid & 63, wave = tid >> 6;
  const int wr = (wave >> 1) * (BM / 2), wc = (wave & 1) * (BN / 2);
#pragma unroll 1
  for (int t = 0; t < 8; ++t) {            // K = 512, BK = 64
    const int k0 = t * 64;
#pragma unroll
    for (int r = 0; r < BM / 32; ++r) {
      int o = r * 4096 + tid * 16;
      int row = o >> 7;
      int ce = (((o & 127) ^ ((row & 7) << 4)) >> 1);   // pre-swizzled src col
      gload16(A + (size_t)(m0 + row) * 512 + k0 + ce, LA + o);
    }
#pragma unroll
    for (int r = 0; r < BN / 32; ++r) {
      int o = r * 4096 + tid * 16;
      int row = o >> 7;
      int ce = (((o & 127) ^ ((row & 7) << 4)) >> 1);
      gload16(Bm + (size_t)(n0 + row) * 512 + k0 + ce, LB + o);
    }
    __syncthreads();                       // tile ready (vmcnt drained)
#pragma unroll
    for (int kk = 0; kk < 2; ++kk) {
      s8v af[FM], bf[FN];
#pragma unroll
      for (int m = 0; m < FM; ++m) {
        int row = wr + m * 16 + (lane & 15);
        int ad = ((row << 7) + kk * 64 + ((lane >> 4) << 4)) ^ ((row & 7) << 4);
        af[m] = *reinterpret_cast<const s8v*>(LA + ad);
      }
#pragma unroll
      for (int n = 0; n < FN; ++n) {
        int row = wc + n * 16 + (lane & 15);
        int ad = ((row << 7) + kk * 64 + ((lane >> 4) << 4)) ^ ((row & 7) << 4);
        bf[n] = *reinterpret_cast<const s8v*>(LB + ad);
      }
#pragma unroll
      for (int m = 0; m < FM; ++m)
#pragma unroll
        for (int n = 0; n < FN; ++n)
          acc[m][n] = mfma16(af[m], bf[n], acc[m][n]);
    }
    if (t + 1 < 8) __syncthreads();        // reads done before next overwrite
  }
}

// ---------------- stage: gemm<0> + qkv/gate epilogue -------------------------
__device__ __forceinline__ void st_gemm0(int vid, int tid, char* arena,
    const short* __restrict__ xnb, const short* __restrict__ wT,
    short* __restrict__ qkvb, const float* __restrict__ b_qkv,
    const float* __restrict__ b_a, float* __restrict__ araw,
    float* __restrict__ csum) {
  const int lane = tid & 63, wave = tid >> 6;
  int xcd = vid & 7, rq = vid >> 3;
  int bx = rq & 15, by = xcd * 4 + (rq >> 4);      // bijective XCD swizzle
  int m0 = by * 128, n0 = bx * 128;
  f32x4 acc[4][4] = {};
  gemm_core<128, 128, 4, 4>(xnb, wT, arena, arena + 16384, m0, n0, tid, acc);
  int wr = (wave >> 1) * 64, wc = (wave & 1) * 64;
  if (n0 < 1536) {
#pragma unroll
    for (int m = 0; m < 4; ++m)
#pragma unroll
      for (int n = 0; n < 4; ++n)
#pragma unroll
        for (int r = 0; r < 4; ++r) {
          int row = m0 + wr + m * 16 + ((lane >> 4) << 2) + r;
          int col = n0 + wc + n * 16 + (lane & 15);
          float v = acc[m][n][r] + b_qkv[col];
          int w = col >> 9, h = (col >> 6) & 7, d = col & 63;
          int b = row >> 11, nn = row & 2047;
          qkvb[((((size_t)(w * 2 + b)) * 8 + h) * 2048 + nn) * 64 + d] = (short)f2b(v);
        }
  } else {
    float cs[4] = {};
    int b = m0 >> 11;
#pragma unroll
    for (int m = 0; m < 4; ++m)
#pragma unroll
      for (int n = 0; n < 4; ++n)
#pragma unroll
        for (int r = 0; r < 4; ++r) {
          int row = m0 + wr + m * 16 + ((lane >> 4) << 2) + r;
          int gc = n0 + wc + n * 16 + (lane & 15) - 1536;
          int h = gc >> 6, d = gc & 63, nn = row & 2047;
          float xv = acc[m][n][r] + b_a[gc];
          araw[((size_t)(b * 8 + h) * 2048 + nn) * 64 + d] = xv;
          float a = 1.f / (1.f + expf(-xv));
          a = fminf(fmaxf(a, 1e-10f), 1.f);
          cs[n] += logf(a);
        }
#pragma unroll
    for (int n = 0; n < 4; ++n) {
      cs[n] += __shfl_xor(cs[n], 16, 64);
      cs[n] += __shfl_xor(cs[n], 32, 64);
    }
    int nsel = lane >> 4;
    float v = (nsel == 0) ? cs[0] : (nsel == 1) ? cs[1] : (nsel == 2) ? cs[2] : cs[3];
    int col = wc + nsel * 16 + (lane & 15);
    int gc = n0 + col - 1536;
    int h = gc >> 6, d = gc & 63;
    int chunkg = ((m0 & 2047) >> 6) + (wave >> 1);
    csum[(((size_t)(b * 8 + h)) * 32 + chunkg) * 64 + d] = v;
  }
}

// chunk-prefix over csum with fixed-32 unroll (independent loads, masked add;
// adding +0.0f is exact identity -> bit-identical to the dynamic loop)
__device__ __forceinline__ float csum_prefix(const float* __restrict__ csum,
                                             int bh, int chunk, int d) {
  float pre = 0.f;
#pragma unroll
  for (int c = 0; c < 32; ++c) {
    float cv = csum[((size_t)bh * 32 + c) * 64 + d];
    pre += (c < chunk) ? cv : 0.f;
  }
  return pre;
}

// ---------------- fallback stages (R8 path: q2/k2/vT materialized) -----------
__device__ __forceinline__ void st_scan2(int vid, int tid, char* arena,
    const short* __restrict__ qkvb, const float* __restrict__ araw,
    const float* __restrict__ csum, short* __restrict__ q2,
    short* __restrict__ k2, short* __restrict__ vT, short* __restrict__ Sbuf) {
  int chunk = vid & 31, bh = vid >> 5;
  int lane = tid & 63, wave = tid >> 6, d = lane;
  short (*kL)[64] = reinterpret_cast<short (*)[64]>(arena);
  short (*vL)[64] = reinterpret_cast<short (*)[64]>(arena + 8192);
  char* kT  = arena + 16384;
  char* vTl = arena + 24576;
  float (*wsum)[64] = reinterpret_cast<float (*)[64]>(arena + 16384);
  float pre = csum_prefix(csum, bh, chunk, d);
  const float* ap = araw + ((size_t)bh * 2048 + chunk * 64 + wave * 16) * 64 + d;
  float la[16]; float run = 0.f;
#pragma unroll
  for (int rr = 0; rr < 16; ++rr) {
    float xv = ap[rr * 64];
    float a = 1.f / (1.f + expf(-xv));
    a = fminf(fmaxf(a, 1e-10f), 1.f);
    run += logf(a);
    la[rr] = run;
  }
  wsum[wave][d] = run;
  __syncthreads();
#pragma unroll
  for (int w = 0; w < 3; ++w) if (w < wave) pre += wsum[w][d];
  const size_t WS = (size_t)2 * 8 * 2048 * 64;
  size_t base = ((size_t)bh * 2048 + chunk * 64 + wave * 16) * 64 + d;
#pragma unroll 4
  for (int rr = 0; rr < 16; ++rr) {
    int r = wave * 16 + rr;
    float g = expf(pre + la[rr]);
    float gi = 1.f / fmaxf(g, 1e-8f);
    float qv = b2f((unsigned short)qkvb[base + rr * 64]);
    float kv = b2f((unsigned short)qkvb[base + WS + rr * 64]);
    short vb = qkvb[base + 2 * WS + rr * 64];
    q2[base + rr * 64] = (short)f2b(qv * 0.125f * g);
    unsigned short kb = f2b(kv * gi);
    k2[base + rr * 64] = (short)kb;
    kL[r][d] = (short)kb;
    vL[r][d] = vb;
  }
  __syncthreads();
  short* vTrow = vT + ((size_t)bh * 64 + d) * 2048 + chunk * 64;
#pragma unroll
  for (int gg = 0; gg < 2; ++gg) {
    int g8 = wave + gg * 4;
    s8v pk, pv;
#pragma unroll
    for (int j = 0; j < 8; ++j) { pk[j] = kL[g8 * 8 + j][d]; pv[j] = vL[g8 * 8 + j][d]; }
    *reinterpret_cast<s8v*>(vTrow + g8 * 8) = pv;
    int ad = ((d << 7) + g8 * 16) ^ ((d & 7) << 4);
    *reinterpret_cast<s8v*>(kT  + ad) = pk;
    *reinterpret_cast<s8v*>(vTl + ad) = pv;
  }
  __syncthreads();
  f32x4 acc[4] = {};
#pragma unroll
  for (int kk = 0; kk < 2; ++kk) {
    int arow = wave * 16 + (lane & 15);
    int aad = ((arow << 7) + kk * 64 + ((lane >> 4) << 4)) ^ ((arow & 7) << 4);
    s8v av = *reinterpret_cast<const s8v*>(vTl + aad);
#pragma unroll
    for (int n = 0; n < 4; ++n) {
      int brow = n * 16 + (lane & 15);
      int bad = ((brow << 7) + kk * 64 + ((lane >> 4) << 4)) ^ ((brow & 7) << 4);
      acc[n] = mfma16(av, *reinterpret_cast<const s8v*>(kT + bad), acc[n]);
    }
  }
  short* Sp = Sbuf + ((size_t)bh * 32 + chunk) * 4096;
#pragma unroll
  for (int n = 0; n < 4; ++n)
#pragma unroll
    for (int r = 0; r < 4; ++r)
      Sp[(wave * 16 + ((lane >> 4) << 2) + r) * 64 + n * 16 + (lane & 15)] = (short)f2b(acc[n][r]);
}

// sprefix: 32 unrolled independent loads first, then the register scan.
__device__ __forceinline__ void st_sprefix(int vid, int tid,
    const short* __restrict__ Sbuf, short* __restrict__ Spre) {
  int bh = vid >> 4;
  int e = ((vid & 15) << 8) + tid;
  size_t base = (size_t)bh * 32 * 4096 + e;
  unsigned short v[32];
#pragma unroll
  for (int c = 0; c < 32; ++c)
    v[c] = (unsigned short)Sbuf[base + (size_t)c * 4096];
  float acc = 0.f;
#pragma unroll
  for (int c = 0; c < 32; ++c) {
    Spre[base + (size_t)c * 4096] = (short)f2b(acc);
    acc += b2f(v[c]);
  }
}

__device__ __forceinline__ void st_attnk(int vid, int tid, char* arena,
    const short* __restrict__ q2, const short* __restrict__ k2,
    const short* __restrict__ vT, const short* __restrict__ Spre,
    short* __restrict__ aout) {
  int chunk = vid & 31, bh = vid >> 5;
  int lane = tid & 63, wave = tid >> 6;
  char* LQ = arena;              // later reused for P
  char* LK = arena + 8192;
  char* LV = arena + 16384;
  char* LS = arena + 24576;
#pragma unroll
  for (int rr = 0; rr < 2; ++rr) {
    int o = rr * 4096 + tid * 16;
    int row = o >> 7;
    int ce = (((o & 127) ^ ((row & 7) << 4)) >> 1);
    gload16(q2   + ((size_t)bh * 2048 + chunk * 64 + row) * 64 + ce, LQ + o);
    gload16(k2   + ((size_t)bh * 2048 + chunk * 64 + row) * 64 + ce, LK + o);
    gload16(vT   + ((size_t)bh * 64 + row) * 2048 + chunk * 64 + ce, LV + o);
    gload16(Spre + (((size_t)bh * 32 + chunk) * 64 + row) * 64 + ce, LS + o);
  }
  __syncthreads();
  f32x4 accS[4] = {}, accO[4] = {};
#pragma unroll
  for (int kk = 0; kk < 2; ++kk) {
    int arow = wave * 16 + (lane & 15);
    int aad = ((arow << 7) + kk * 64 + ((lane >> 4) << 4)) ^ ((arow & 7) << 4);
    s8v aq = *reinterpret_cast<const s8v*>(LQ + aad);
#pragma unroll
    for (int n = 0; n < 4; ++n) {
      int brow = n * 16 + (lane & 15);
      int bad = ((brow << 7) + kk * 64 + ((lane >> 4) << 4)) ^ ((brow & 7) << 4);
      accS[n] = mfma16(aq, *reinterpret_cast<const s8v*>(LK + bad), accS[n]);
      accO[n] = mfma16(aq, *reinterpret_cast<const s8v*>(LS + bad), accO[n]);
    }
  }
  __syncthreads();
#pragma unroll
  for (int n = 0; n < 4; ++n)
#pragma unroll
    for (int r = 0; r < 4; ++r) {
      int i = wave * 16 + ((lane >> 4) << 2) + r;
      int j = n * 16 + (lane & 15);
      float v = (j <= i) ? accS[n][r] : 0.f;
      int ad = ((i << 7) + (j << 1)) ^ ((i & 7) << 4);
      *reinterpret_cast<short*>(LQ + ad) = (short)f2b(v);
    }
  __syncthreads();
#pragma unroll
  for (int kk = 0; kk < 2; ++kk) {
    int arow = wave * 16 + (lane & 15);
    int aad = ((arow << 7) + kk * 64 + ((lane >> 4) << 4)) ^ ((arow & 7) << 4);
    s8v ap = *reinterpret_cast<const s8v*>(LQ + aad);
#pragma unroll
    for (int n = 0; n < 4; ++n) {
      int brow = n * 16 + (lane & 15);
      int bad = ((brow << 7) + kk * 64 + ((lane >> 4) << 4)) ^ ((brow & 7) << 4);
      accO[n] = mfma16(ap, *reinterpret_cast<const s8v*>(LV + bad), accO[n]);
    }
  }
  int b = bh >> 3, h = bh & 7;
#pragma unroll
  for (int n = 0; n < 4; ++n)
#pragma unroll
    for (int r = 0; r < 4; ++r) {
      int i = wave * 16 + ((lane >> 4) << 2) + r;
      int col = h * 64 + n * 16 + (lane & 15);
      size_t row = (size_t)b * 2048 + chunk * 64 + i;
      aout[row * 512 + col] = (short)f2b(accO[n][r]);
    }
}

// ---------------- stage: gemm<1> (output projection) -------------------------
__device__ __forceinline__ void st_gemm1(int vid, int tid, char* arena,
    const short* __restrict__ aout, const short* __restrict__ woT,
    float* __restrict__ out, const float* __restrict__ b_out) {
  const int lane = tid & 63, wave = tid >> 6;
  int xcd = vid & 7, rq = vid >> 3;
  int bx = rq & 7, by = xcd * 8 + (rq >> 3);       // bijective XCD swizzle
  int m0 = by * 64, n0 = bx * 64;
  f32x4 acc[2][2] = {};
  gemm_core<64, 64, 2, 2>(aout, woT, arena, arena + 8192, m0, n0, tid, acc);
  int wr = (wave >> 1) * 32, wc = (wave & 1) * 32;
#pragma unroll
  for (int m = 0; m < 2; ++m)
#pragma unroll
    for (int n = 0; n < 2; ++n)
#pragma unroll
      for (int r = 0; r < 4; ++r) {
        int row = m0 + wr + m * 16 + ((lane >> 4) << 2) + r;
        int col = n0 + wc + n * 16 + (lane & 15);
        out[(size_t)row * 512 + col] = acc[m][n][r] + b_out[col];
      }
}

// ---------------- mega kernel (cooperative, persistent-LDS merge) ------------
__global__ __launch_bounds__(256, 2) void mega_k(
    const float* __restrict__ x, const float* __restrict__ gamma,
    const float* __restrict__ w_qkv, const float* __restrict__ b_qkv,
    const float* __restrict__ w_a, const float* __restrict__ b_a,
    const float* __restrict__ w_out, const float* __restrict__ b_out,
    float* __restrict__ out,
    short* __restrict__ xnb, short* __restrict__ wT, short* __restrict__ woT,
    short* __restrict__ qkvb, float* __restrict__ araw, float* __restrict__ csum,
    short* __restrict__ Sbuf, short* __restrict__ Spre, short* __restrict__ aout) {
  __shared__ __align__(16) char arena[32768];
  cg::grid_group grid = cg::this_grid();
  const int bid = blockIdx.x, tid = threadIdx.x;
  const int lane = tid & 63, wave = tid >> 6;

  // ---- S1: prep ----
  for (int u = bid; u < 2304; u += 512)
    st_prep(u, tid, arena, x, gamma, xnb, w_qkv, w_a, w_out, wT, woT);
  __threadfence(); grid.sync();

  // ---- S2: gemm0 ----
  st_gemm0(bid, tid, arena, xnb, wT, qkvb, b_qkv, b_a, araw, csum);
  __threadfence(); grid.sync();

  // ---- S3: gates -> LDS (qL,kR,kT,vTl) + kstate + local causal attention ---
  const int chunk = bid & 31, bh = bid >> 5;
  const int d = lane;
  char* qL  = arena;            // q2 row-major swz   [persists to S5]
  char* kR  = arena + 8192;     // k2 row-major swz   [S5 reuses for Spre]
  char* kT  = arena + 16384;    // k2^T swz           [reused for P]
  char* vTl = arena + 24576;    // v^T swz
  f32x4 accO[4] = {};
  {
    float (*wsum)[64] = reinterpret_cast<float (*)[64]>(kR);  // pre-gate scratch
    float pre = csum_prefix(csum, bh, chunk, d);
    const float* ap = araw + ((size_t)bh * 2048 + chunk * 64 + wave * 16) * 64 + d;
    float la[16]; float run = 0.f;
#pragma unroll
    for (int rr = 0; rr < 16; ++rr) {
      float xv = ap[rr * 64];
      float a = 1.f / (1.f + expf(-xv));
      a = fminf(fmaxf(a, 1e-10f), 1.f);
      run += logf(a);
      la[rr] = run;
    }
    wsum[wave][d] = run;
    __syncthreads();
#pragma unroll
    for (int w = 0; w < 3; ++w) if (w < wave) pre += wsum[w][d];
    __syncthreads();           // wsum reads done before kR is overwritten
    const size_t WS = (size_t)2 * 8 * 2048 * 64;
    size_t base = ((size_t)bh * 2048 + chunk * 64 + wave * 16) * 64 + d;
#pragma unroll 4
    for (int rr = 0; rr < 16; ++rr) {
      int r = wave * 16 + rr;
      float g = expf(pre + la[rr]);            // a_cum
      float gi = 1.f / fmaxf(g, 1e-8f);        // a_cum_inv
      float qv = b2f((unsigned short)qkvb[base + rr * 64]);
      float kv = b2f((unsigned short)qkvb[base + WS + rr * 64]);
      short vb = qkvb[base + 2 * WS + rr * 64];
      unsigned short qb = f2b(qv * 0.125f * g);   // SCALE = 64^-0.5
      unsigned short kb = f2b(kv * gi);
      // row-major swz writes
      int adr = ((r << 7) + (d << 1)) ^ ((r & 7) << 4);
      *reinterpret_cast<short*>(qL + adr) = (short)qb;
      *reinterpret_cast<short*>(kR + adr) = (short)kb;
      // transposed swz writes
      int adt = ((d << 7) + (r << 1)) ^ ((d & 7) << 4);
      *reinterpret_cast<short*>(kT  + adt) = (short)kb;
      *reinterpret_cast<short*>(vTl + adt) = vb;
    }
    __syncthreads();
    // kstate: S^T[dd][d'] = sum_j v[j][dd] k2[j][d']
    f32x4 sacc[4] = {};
#pragma unroll
    for (int kk = 0; kk < 2; ++kk) {
      int arow = wave * 16 + (lane & 15);
      int aad = ((arow << 7) + kk * 64 + ((lane >> 4) << 4)) ^ ((arow & 7) << 4);
      s8v av = *reinterpret_cast<const s8v*>(vTl + aad);
#pragma unroll
      for (int n = 0; n < 4; ++n) {
        int brow = n * 16 + (lane & 15);
        int bad = ((brow << 7) + kk * 64 + ((lane >> 4) << 4)) ^ ((brow & 7) << 4);
        sacc[n] = mfma16(av, *reinterpret_cast<const s8v*>(kT + bad), sacc[n]);
      }
    }
    short* Sp = Sbuf + ((size_t)bh * 32 + chunk) * 4096;
#pragma unroll
    for (int n = 0; n < 4; ++n)
#pragma unroll
      for (int r = 0; r < 4; ++r)
        Sp[(wave * 16 + ((lane >> 4) << 2) + r) * 64 + n * 16 + (lane & 15)] = (short)f2b(sacc[n][r]);
    // scores: sim[i][j] = q2[i]·k2[j]
    f32x4 accS[4] = {};
#pragma unroll
    for (int kk = 0; kk < 2; ++kk) {
      int arow = wave * 16 + (lane & 15);
      int aad = ((arow << 7) + kk * 64 + ((lane >> 4) << 4)) ^ ((arow & 7) << 4);
      s8v aq = *reinterpret_cast<const s8v*>(qL + aad);
#pragma unroll
      for (int n = 0; n < 4; ++n) {
        int brow = n * 16 + (lane & 15);
        int bad = ((brow << 7) + kk * 64 + ((lane >> 4) << 4)) ^ ((brow & 7) << 4);
        accS[n] = mfma16(aq, *reinterpret_cast<const s8v*>(kR + bad), accS[n]);
      }
    }
    __syncthreads();           // kT reads (kstate) done before P overwrites
#pragma unroll
    for (int n = 0; n < 4; ++n)
#pragma unroll
      for (int r = 0; r < 4; ++r) {
        int i = wave * 16 + ((lane >> 4) << 2) + r;
        int j = n * 16 + (lane & 15);
        float v = (j <= i) ? accS[n][r] : 0.f;
        int ad = ((i << 7) + (j << 1)) ^ ((i & 7) << 4);
        *reinterpret_cast<short*>(kT + ad) = (short)f2b(v);
      }
    __syncthreads();
    // PV: accO[i][d'] = sum_j P[i][j] v[j][d']
#pragma unroll
    for (int kk = 0; kk < 2; ++kk) {
      int arow = wave * 16 + (lane & 15);
      int aad = ((arow << 7) + kk * 64 + ((lane >> 4) << 4)) ^ ((arow & 7) << 4);
      s8v ap = *reinterpret_cast<const s8v*>(kT + aad);
#pragma unroll
      for (int n = 0; n < 4; ++n) {
        int brow = n * 16 + (lane & 15);
        int bad = ((brow << 7) + kk * 64 + ((lane >> 4) << 4)) ^ ((brow & 7) << 4);
        accO[n] = mfma16(ap, *reinterpret_cast<const s8v*>(vTl + bad), accO[n]);
      }
    }
  }
  __threadfence(); grid.sync();

  // ---- S4: sprefix (parallel loads; qL + accO persist in all blocks) ----
  if (bid < 256) st_sprefix(bid, tid, Sbuf, Spre);
  __threadfence(); grid.sync();

  // ---- S5: accO += q2 @ Spre; write aout ----
  {
    char* LS = kR;             // reuse kR area (linear dest for gload16)
#pragma unroll
    for (int rr = 0; rr < 2; ++rr) {
      int o = rr * 4096 + tid * 16;
      int row = o >> 7;
      int ce = (((o & 127) ^ ((row & 7) << 4)) >> 1);
      gload16(Spre + (((size_t)bh * 32 + chunk) * 64 + row) * 64 + ce, LS + o);
    }
    __syncthreads();
#pragma unroll
    for (int kk = 0; kk < 2; ++kk) {
      int arow = wave * 16 + (lane & 15);
      int aad = ((arow << 7) + kk * 64 + ((lane >> 4) << 4)) ^ ((arow & 7) << 4);
      s8v aq = *reinterpret_cast<const s8v*>(qL + aad);
#pragma unroll
      for (int n = 0; n < 4; ++n) {
        int brow = n * 16 + (lane & 15);
        int bad = ((brow << 7) + kk * 64 + ((lane >> 4) << 4)) ^ ((brow & 7) << 4);
        accO[n] = mfma16(aq, *reinterpret_cast<const s8v*>(LS + bad), accO[n]);
      }
    }
    int b = bh >> 3, h = bh & 7;
#pragma unroll
    for (int n = 0; n < 4; ++n)
#pragma unroll
      for (int r = 0; r < 4; ++r) {
        int i = wave * 16 + ((lane >> 4) << 2) + r;
        int col = h * 64 + n * 16 + (lane & 15);
        size_t row = (size_t)b * 2048 + chunk * 64 + i;
        aout[row * 512 + col] = (short)f2b(accO[n][r]);
      }
  }
  __threadfence(); grid.sync();

  // ---- S6: gemm1 ----
  st_gemm1(bid, tid, arena, aout, woT, out, b_out);
}

// ---------------- fallback wrappers (R8 proven path) -------------------------
__global__ __launch_bounds__(256) void prep_k(const float* x, const float* gamma,
    short* xnb, const float* w_qkv, const float* w_a, const float* w_out,
    short* wT, short* woT) {
  __shared__ __align__(16) char arena[4224];
  st_prep(blockIdx.x, threadIdx.x, arena, x, gamma, xnb, w_qkv, w_a, w_out, wT, woT);
}
__global__ __launch_bounds__(256) void gemm0_k(const short* xnb, const short* wT,
    short* qkvb, const float* b_qkv, const float* b_a, float* araw, float* csum) {
  __shared__ __align__(16) char arena[32768];
  st_gemm0(blockIdx.x, threadIdx.x, arena, xnb, wT, qkvb, b_qkv, b_a, araw, csum);
}
__global__ __launch_bounds__(256) void scan2_k(const short* qkvb, const float* araw,
    const float* csum, short* q2, short* k2, short* vT, short* Sbuf) {
  __shared__ __align__(16) char arena[32768];
  st_scan2(blockIdx.x, threadIdx.x, arena, qkvb, araw, csum, q2, k2, vT, Sbuf);
}
__global__ __launch_bounds__(256) void sprefix_k(const short* Sbuf, short* Spre) {
  st_sprefix(blockIdx.x, threadIdx.x, Sbuf, Spre);
}
__global__ __launch_bounds__(256) void attnk_k(const short* q2, const short* k2,
    const short* vT, const short* Spre, short* aout) {
  __shared__ __align__(16) char arena[32768];
  st_attnk(blockIdx.x, threadIdx.x, arena, q2, k2, vT, Spre, aout);
}
__global__ __launch_bounds__(256) void gemm1_k(const short* aout, const short* woT,
    float* out, const float* b_out) {
  __shared__ __align__(16) char arena[16384];
  st_gemm1(blockIdx.x, threadIdx.x, arena, aout, woT, out, b_out);
}

// ---------------------------------------------------------------------------
extern "C" void kernel_launch(void* const* d_in, const int* in_sizes, int n_in,
                              void* d_out, int out_size, void* d_ws, size_t ws_size,
                              hipStream_t stream) {
  const float* x     = (const float*)d_in[0];
  const float* gamma = (const float*)d_in[1];
  const float* w_qkv = (const float*)d_in[2];
  const float* b_qkv = (const float*)d_in[3];
  const float* w_a   = (const float*)d_in[4];
  const float* b_a   = (const float*)d_in[5];
  const float* w_out = (const float*)d_in[6];
  const float* b_out = (const float*)d_in[7];
  float* out = (float*)d_out;
  char* ws = (char*)d_ws;

  const size_t MB = 1u << 20;
  short* xnb  = (short*)(ws);                 // 4 MiB   [4096][512] bf16
  short* wT   = (short*)(ws + 4  * MB);       // 2 MiB   [2048][512] bf16
  short* woT  = (short*)(ws + 6  * MB);       // 0.5 MiB [512][512]  bf16
  short* qkvb = (short*)(ws + 7  * MB);       // 12 MiB  [3][2][8][2048][64] bf16
  float* araw = (float*)(ws + 19 * MB);       // 8 MiB   [16][2048][64] f32
  float* csum = (float*)(ws + 27 * MB);       // 128 KiB [16][32][64] f32
  short* Sbuf = (short*)(ws + 28 * MB);       // 4 MiB   [16][32][64][64] bf16
  short* Spre = (short*)(ws + 32 * MB);       // 4 MiB
  short* aout = (short*)(ws + 36 * MB);       // 4 MiB   [4096][512] bf16
  // fallback-only buffers:
  short* q2   = (short*)(ws + 40 * MB);       // 4 MiB
  short* k2   = (short*)(ws + 44 * MB);       // 4 MiB
  short* vT   = (short*)(ws + 48 * MB);       // 4 MiB

  int dev = 0; (void)hipGetDevice(&dev);
  int coop = 0;
  (void)hipDeviceGetAttribute(&coop, hipDeviceAttributeCooperativeLaunch, dev);
  int nb = 0;
  (void)hipOccupancyMaxActiveBlocksPerMultiprocessor(&nb, mega_k, 256, 0);

  hipError_t err = hipErrorUnknown;
  if (coop && nb >= 2) {
    void* args[] = {&x, &gamma, &w_qkv, &b_qkv, &w_a, &b_a, &w_out, &b_out,
                    &out, &xnb, &wT, &woT, &qkvb, &araw, &csum,
                    &Sbuf, &Spre, &aout};
    err = hipLaunchCooperativeKernel((void*)mega_k, dim3(512), dim3(256), args, 0, stream);
  }
  if (err != hipSuccess) {
    prep_k   <<<2304, 256, 0, stream>>>(x, gamma, xnb, w_qkv, w_a, w_out, wT, woT);
    gemm0_k  <<<512,  256, 0, stream>>>(xnb, wT, qkvb, b_qkv, b_a, araw, csum);
    scan2_k  <<<512,  256, 0, stream>>>(qkvb, araw, csum, q2, k2, vT, Sbuf);
    sprefix_k<<<256,  256, 0, stream>>>(Sbuf, Spre);
    attnk_k  <<<512,  256, 0, stream>>>(q2, k2, vT, Spre, aout);
    gemm1_k  <<<512,  256, 0, stream>>>(aout, woT, out, b_out);
  }
}

// Round 11
// 61.446 us; speedup vs baseline: 1.1578x; 1.0047x over previous
//
#include <hip/hip_runtime.h>
#include <hip/hip_cooperative_groups.h>

// ---------------------------------------------------------------------------
// CausalFullAttention (decay-gated causal linear attention), MI355X gfx950
// b=2, n=2048, DIM=512, HEADS=8, DIM_HEAD=64
// R11: == R10 + S4 (sprefix) merged into S5: each (chunk,bh) block computes
//      its own exclusive chunk-prefix of Sbuf in fp32 registers (bit-identical
//      order), writes bf16 into the LDS B-operand layout, then accO += q@Spre.
//      Removes one grid.sync, the half-idle sprefix stage, and the Spre
//      global round-trip. 4 grid.syncs total. Fallback path unchanged.
// ---------------------------------------------------------------------------

namespace cg = cooperative_groups;

using s8v   = __attribute__((ext_vector_type(8))) short;   // 8 x bf16 bits
using f32x4 = __attribute__((ext_vector_type(4))) float;

__device__ __forceinline__ unsigned short f2b(float f) {
  unsigned int u = __builtin_bit_cast(unsigned int, f);
  u += 0x7FFFu + ((u >> 16) & 1u);          // RNE
  return (unsigned short)(u >> 16);
}
__device__ __forceinline__ float b2f(unsigned short b) {
  unsigned int u = ((unsigned int)b) << 16;
  return __builtin_bit_cast(float, u);
}
__device__ __forceinline__ f32x4 mfma16(s8v a, s8v b, f32x4 c) {
  return __builtin_amdgcn_mfma_f32_16x16x32_bf16(a, b, c, 0, 0, 0);
}
__device__ __forceinline__ void gload16(const void* g, void* l) {
  __builtin_amdgcn_global_load_lds(
      (const __attribute__((address_space(1))) void*)g,
      (__attribute__((address_space(3))) void*)l, 16, 0, 0);
}

// ---------------- stage: prep (rmsnorm u<1024 | wtrans u>=1024) --------------
__device__ __forceinline__ void st_prep(int u, int tid, char* arena,
    const float* __restrict__ x, const float* __restrict__ gamma,
    short* __restrict__ xnb,
    const float* __restrict__ w_qkv, const float* __restrict__ w_a,
    const float* __restrict__ w_out,
    short* __restrict__ wT, short* __restrict__ woT) {
  int lane = tid & 63, wave = tid >> 6;
  if (u < 1024) {
    int row = u * 4 + wave;
    const float4* xp = reinterpret_cast<const float4*>(x + (size_t)row * 512 + lane * 8);
    float4 v0 = xp[0], v1 = xp[1];
    float ss = v0.x*v0.x + v0.y*v0.y + v0.z*v0.z + v0.w*v0.w
             + v1.x*v1.x + v1.y*v1.y + v1.z*v1.z + v1.w*v1.w;
#pragma unroll
    for (int off = 32; off > 0; off >>= 1) ss += __shfl_xor(ss, off, 64);
    float s = 22.627416997969522f / fmaxf(sqrtf(ss), 1e-12f);
    const float* g = gamma + lane * 8;
    float vals[8] = {v0.x, v0.y, v0.z, v0.w, v1.x, v1.y, v1.z, v1.w};
    s8v o;
#pragma unroll
    for (int j = 0; j < 8; ++j) o[j] = (short)f2b(vals[j] * s * g[j]);
    *reinterpret_cast<s8v*>(xnb + (size_t)row * 512 + lane * 8) = o;
  } else {
    float (*t)[33] = reinterpret_cast<float (*)[33]>(arena);
    int id = u - 1024;
    int bx = id % 80, k0 = (id / 80) * 32;
    const float* src; short* dst; int N, n0;
    if (bx < 48)      { src = w_qkv; dst = wT;                      N = 1536; n0 = bx * 32; }
    else if (bx < 64) { src = w_a;   dst = wT + (size_t)1536 * 512; N = 512;  n0 = (bx - 48) * 32; }
    else              { src = w_out; dst = woT;                     N = 512;  n0 = (bx - 64) * 32; }
    int tx = tid & 31, ty = tid >> 5;
    __syncthreads();   // prior arena use complete
#pragma unroll
    for (int i = 0; i < 4; ++i)
      t[ty + 8 * i][tx] = src[(size_t)(k0 + ty + 8 * i) * N + n0 + tx];
    __syncthreads();
#pragma unroll
    for (int i = 0; i < 4; ++i)
      dst[(size_t)(n0 + ty + 8 * i) * 512 + k0 + tx] = (short)f2b(t[tx][ty + 8 * i]);
  }
}

// ---------------- shared single-buffered GEMM core (m97 structure) -----------
template <int BM, int BN, int FM, int FN>
__device__ __forceinline__ void gemm_core(const short* __restrict__ A,
                                          const short* __restrict__ Bm,
                                          char* LA, char* LB,
                                          int m0, int n0, int tid,
                                          f32x4 (&acc)[FM][FN]) {
  const int lane = tid & 63, wave = tid >> 6;
  const int wr = (wave >> 1) * (BM / 2), wc = (wave & 1) * (BN / 2);
#pragma unroll 1
  for (int t = 0; t < 8; ++t) {            // K = 512, BK = 64
    const int k0 = t * 64;
#pragma unroll
    for (int r = 0; r < BM / 32; ++r) {
      int o = r * 4096 + tid * 16;
      int row = o >> 7;
      int ce = (((o & 127) ^ ((row & 7) << 4)) >> 1);   // pre-swizzled src col
      gload16(A + (size_t)(m0 + row) * 512 + k0 + ce, LA + o);
    }
#pragma unroll
    for (int r = 0; r < BN / 32; ++r) {
      int o = r * 4096 + tid * 16;
      int row = o >> 7;
      int ce = (((o & 127) ^ ((row & 7) << 4)) >> 1);
      gload16(Bm + (size_t)(n0 + row) * 512 + k0 + ce, LB + o);
    }
    __syncthreads();                       // tile ready (vmcnt drained)
#pragma unroll
    for (int kk = 0; kk < 2; ++kk) {
      s8v af[FM], bf[FN];
#pragma unroll
      for (int m = 0; m < FM; ++m) {
        int row = wr + m * 16 + (lane & 15);
        int ad = ((row << 7) + kk * 64 + ((lane >> 4) << 4)) ^ ((row & 7) << 4);
        af[m] = *reinterpret_cast<const s8v*>(LA + ad);
      }
#pragma unroll
      for (int n = 0; n < FN; ++n) {
        int row = wc + n * 16 + (lane & 15);
        int ad = ((row << 7) + kk * 64 + ((lane >> 4) << 4)) ^ ((row & 7) << 4);
        bf[n] = *reinterpret_cast<const s8v*>(LB + ad);
      }
#pragma unroll
      for (int m = 0; m < FM; ++m)
#pragma unroll
        for (int n = 0; n < FN; ++n)
          acc[m][n] = mfma16(af[m], bf[n], acc[m][n]);
    }
    if (t + 1 < 8) __syncthreads();        // reads done before next overwrite
  }
}

// ---------------- stage: gemm<0> + qkv/gate epilogue -------------------------
__device__ __forceinline__ void st_gemm0(int vid, int tid, char* arena,
    const short* __restrict__ xnb, const short* __restrict__ wT,
    short* __restrict__ qkvb, const float* __restrict__ b_qkv,
    const float* __restrict__ b_a, float* __restrict__ araw,
    float* __restrict__ csum) {
  const int lane = tid & 63, wave = tid >> 6;
  int xcd = vid & 7, rq = vid >> 3;
  int bx = rq & 15, by = xcd * 4 + (rq >> 4);      // bijective XCD swizzle
  int m0 = by * 128, n0 = bx * 128;
  f32x4 acc[4][4] = {};
  gemm_core<128, 128, 4, 4>(xnb, wT, arena, arena + 16384, m0, n0, tid, acc);
  int wr = (wave >> 1) * 64, wc = (wave & 1) * 64;
  if (n0 < 1536) {
#pragma unroll
    for (int m = 0; m < 4; ++m)
#pragma unroll
      for (int n = 0; n < 4; ++n)
#pragma unroll
        for (int r = 0; r < 4; ++r) {
          int row = m0 + wr + m * 16 + ((lane >> 4) << 2) + r;
          int col = n0 + wc + n * 16 + (lane & 15);
          float v = acc[m][n][r] + b_qkv[col];
          int w = col >> 9, h = (col >> 6) & 7, d = col & 63;
          int b = row >> 11, nn = row & 2047;
          qkvb[((((size_t)(w * 2 + b)) * 8 + h) * 2048 + nn) * 64 + d] = (short)f2b(v);
        }
  } else {
    float cs[4] = {};
    int b = m0 >> 11;
#pragma unroll
    for (int m = 0; m < 4; ++m)
#pragma unroll
      for (int n = 0; n < 4; ++n)
#pragma unroll
        for (int r = 0; r < 4; ++r) {
          int row = m0 + wr + m * 16 + ((lane >> 4) << 2) + r;
          int gc = n0 + wc + n * 16 + (lane & 15) - 1536;
          int h = gc >> 6, d = gc & 63, nn = row & 2047;
          float xv = acc[m][n][r] + b_a[gc];
          araw[((size_t)(b * 8 + h) * 2048 + nn) * 64 + d] = xv;
          float a = 1.f / (1.f + expf(-xv));
          a = fminf(fmaxf(a, 1e-10f), 1.f);
          cs[n] += logf(a);
        }
#pragma unroll
    for (int n = 0; n < 4; ++n) {
      cs[n] += __shfl_xor(cs[n], 16, 64);
      cs[n] += __shfl_xor(cs[n], 32, 64);
    }
    int nsel = lane >> 4;
    float v = (nsel == 0) ? cs[0] : (nsel == 1) ? cs[1] : (nsel == 2) ? cs[2] : cs[3];
    int col = wc + nsel * 16 + (lane & 15);
    int gc = n0 + col - 1536;
    int h = gc >> 6, d = gc & 63;
    int chunkg = ((m0 & 2047) >> 6) + (wave >> 1);
    csum[(((size_t)(b * 8 + h)) * 32 + chunkg) * 64 + d] = v;
  }
}

// chunk-prefix over csum with fixed-32 unroll (independent loads, masked add)
__device__ __forceinline__ float csum_prefix(const float* __restrict__ csum,
                                             int bh, int chunk, int d) {
  float pre = 0.f;
#pragma unroll
  for (int c = 0; c < 32; ++c) {
    float cv = csum[((size_t)bh * 32 + c) * 64 + d];
    pre += (c < chunk) ? cv : 0.f;
  }
  return pre;
}

// ---------------- fallback stages (R8 path: q2/k2/vT materialized) -----------
__device__ __forceinline__ void st_scan2(int vid, int tid, char* arena,
    const short* __restrict__ qkvb, const float* __restrict__ araw,
    const float* __restrict__ csum, short* __restrict__ q2,
    short* __restrict__ k2, short* __restrict__ vT, short* __restrict__ Sbuf) {
  int chunk = vid & 31, bh = vid >> 5;
  int lane = tid & 63, wave = tid >> 6, d = lane;
  short (*kL)[64] = reinterpret_cast<short (*)[64]>(arena);
  short (*vL)[64] = reinterpret_cast<short (*)[64]>(arena + 8192);
  char* kT  = arena + 16384;
  char* vTl = arena + 24576;
  float (*wsum)[64] = reinterpret_cast<float (*)[64]>(arena + 16384);
  float pre = csum_prefix(csum, bh, chunk, d);
  const float* ap = araw + ((size_t)bh * 2048 + chunk * 64 + wave * 16) * 64 + d;
  float la[16]; float run = 0.f;
#pragma unroll
  for (int rr = 0; rr < 16; ++rr) {
    float xv = ap[rr * 64];
    float a = 1.f / (1.f + expf(-xv));
    a = fminf(fmaxf(a, 1e-10f), 1.f);
    run += logf(a);
    la[rr] = run;
  }
  wsum[wave][d] = run;
  __syncthreads();
#pragma unroll
  for (int w = 0; w < 3; ++w) if (w < wave) pre += wsum[w][d];
  const size_t WS = (size_t)2 * 8 * 2048 * 64;
  size_t base = ((size_t)bh * 2048 + chunk * 64 + wave * 16) * 64 + d;
#pragma unroll 4
  for (int rr = 0; rr < 16; ++rr) {
    int r = wave * 16 + rr;
    float g = expf(pre + la[rr]);
    float gi = 1.f / fmaxf(g, 1e-8f);
    float qv = b2f((unsigned short)qkvb[base + rr * 64]);
    float kv = b2f((unsigned short)qkvb[base + WS + rr * 64]);
    short vb = qkvb[base + 2 * WS + rr * 64];
    q2[base + rr * 64] = (short)f2b(qv * 0.125f * g);
    unsigned short kb = f2b(kv * gi);
    k2[base + rr * 64] = (short)kb;
    kL[r][d] = (short)kb;
    vL[r][d] = vb;
  }
  __syncthreads();
  short* vTrow = vT + ((size_t)bh * 64 + d) * 2048 + chunk * 64;
#pragma unroll
  for (int gg = 0; gg < 2; ++gg) {
    int g8 = wave + gg * 4;
    s8v pk, pv;
#pragma unroll
    for (int j = 0; j < 8; ++j) { pk[j] = kL[g8 * 8 + j][d]; pv[j] = vL[g8 * 8 + j][d]; }
    *reinterpret_cast<s8v*>(vTrow + g8 * 8) = pv;
    int ad = ((d << 7) + g8 * 16) ^ ((d & 7) << 4);
    *reinterpret_cast<s8v*>(kT  + ad) = pk;
    *reinterpret_cast<s8v*>(vTl + ad) = pv;
  }
  __syncthreads();
  f32x4 acc[4] = {};
#pragma unroll
  for (int kk = 0; kk < 2; ++kk) {
    int arow = wave * 16 + (lane & 15);
    int aad = ((arow << 7) + kk * 64 + ((lane >> 4) << 4)) ^ ((arow & 7) << 4);
    s8v av = *reinterpret_cast<const s8v*>(vTl + aad);
#pragma unroll
    for (int n = 0; n < 4; ++n) {
      int brow = n * 16 + (lane & 15);
      int bad = ((brow << 7) + kk * 64 + ((lane >> 4) << 4)) ^ ((brow & 7) << 4);
      acc[n] = mfma16(av, *reinterpret_cast<const s8v*>(kT + bad), acc[n]);
    }
  }
  short* Sp = Sbuf + ((size_t)bh * 32 + chunk) * 4096;
#pragma unroll
  for (int n = 0; n < 4; ++n)
#pragma unroll
    for (int r = 0; r < 4; ++r)
      Sp[(wave * 16 + ((lane >> 4) << 2) + r) * 64 + n * 16 + (lane & 15)] = (short)f2b(acc[n][r]);
}

__device__ __forceinline__ void st_sprefix(int vid, int tid,
    const short* __restrict__ Sbuf, short* __restrict__ Spre) {
  int bh = vid >> 4;
  int e = ((vid & 15) << 8) + tid;
  size_t base = (size_t)bh * 32 * 4096 + e;
  unsigned short v[32];
#pragma unroll
  for (int c = 0; c < 32; ++c)
    v[c] = (unsigned short)Sbuf[base + (size_t)c * 4096];
  float acc = 0.f;
#pragma unroll
  for (int c = 0; c < 32; ++c) {
    Spre[base + (size_t)c * 4096] = (short)f2b(acc);
    acc += b2f(v[c]);
  }
}

__device__ __forceinline__ void st_attnk(int vid, int tid, char* arena,
    const short* __restrict__ q2, const short* __restrict__ k2,
    const short* __restrict__ vT, const short* __restrict__ Spre,
    short* __restrict__ aout) {
  int chunk = vid & 31, bh = vid >> 5;
  int lane = tid & 63, wave = tid >> 6;
  char* LQ = arena;              // later reused for P
  char* LK = arena + 8192;
  char* LV = arena + 16384;
  char* LS = arena + 24576;
#pragma unroll
  for (int rr = 0; rr < 2; ++rr) {
    int o = rr * 4096 + tid * 16;
    int row = o >> 7;
    int ce = (((o & 127) ^ ((row & 7) << 4)) >> 1);
    gload16(q2   + ((size_t)bh * 2048 + chunk * 64 + row) * 64 + ce, LQ + o);
    gload16(k2   + ((size_t)bh * 2048 + chunk * 64 + row) * 64 + ce, LK + o);
    gload16(vT   + ((size_t)bh * 64 + row) * 2048 + chunk * 64 + ce, LV + o);
    gload16(Spre + (((size_t)bh * 32 + chunk) * 64 + row) * 64 + ce, LS + o);
  }
  __syncthreads();
  f32x4 accS[4] = {}, accO[4] = {};
#pragma unroll
  for (int kk = 0; kk < 2; ++kk) {
    int arow = wave * 16 + (lane & 15);
    int aad = ((arow << 7) + kk * 64 + ((lane >> 4) << 4)) ^ ((arow & 7) << 4);
    s8v aq = *reinterpret_cast<const s8v*>(LQ + aad);
#pragma unroll
    for (int n = 0; n < 4; ++n) {
      int brow = n * 16 + (lane & 15);
      int bad = ((brow << 7) + kk * 64 + ((lane >> 4) << 4)) ^ ((brow & 7) << 4);
      accS[n] = mfma16(aq, *reinterpret_cast<const s8v*>(LK + bad), accS[n]);
      accO[n] = mfma16(aq, *reinterpret_cast<const s8v*>(LS + bad), accO[n]);
    }
  }
  __syncthreads();
#pragma unroll
  for (int n = 0; n < 4; ++n)
#pragma unroll
    for (int r = 0; r < 4; ++r) {
      int i = wave * 16 + ((lane >> 4) << 2) + r;
      int j = n * 16 + (lane & 15);
      float v = (j <= i) ? accS[n][r] : 0.f;
      int ad = ((i << 7) + (j << 1)) ^ ((i & 7) << 4);
      *reinterpret_cast<short*>(LQ + ad) = (short)f2b(v);
    }
  __syncthreads();
#pragma unroll
  for (int kk = 0; kk < 2; ++kk) {
    int arow = wave * 16 + (lane & 15);
    int aad = ((arow << 7) + kk * 64 + ((lane >> 4) << 4)) ^ ((arow & 7) << 4);
    s8v ap = *reinterpret_cast<const s8v*>(LQ + aad);
#pragma unroll
    for (int n = 0; n < 4; ++n) {
      int brow = n * 16 + (lane & 15);
      int bad = ((brow << 7) + kk * 64 + ((lane >> 4) << 4)) ^ ((brow & 7) << 4);
      accO[n] = mfma16(ap, *reinterpret_cast<const s8v*>(LV + bad), accO[n]);
    }
  }
  int b = bh >> 3, h = bh & 7;
#pragma unroll
  for (int n = 0; n < 4; ++n)
#pragma unroll
    for (int r = 0; r < 4; ++r) {
      int i = wave * 16 + ((lane >> 4) << 2) + r;
      int col = h * 64 + n * 16 + (lane & 15);
      size_t row = (size_t)b * 2048 + chunk * 64 + i;
      aout[row * 512 + col] = (short)f2b(accO[n][r]);
    }
}

// ---------------- stage: gemm<1> (output projection) -------------------------
__device__ __forceinline__ void st_gemm1(int vid, int tid, char* arena,
    const short* __restrict__ aout, const short* __restrict__ woT,
    float* __restrict__ out, const float* __restrict__ b_out) {
  const int lane = tid & 63, wave = tid >> 6;
  int xcd = vid & 7, rq = vid >> 3;
  int bx = rq & 7, by = xcd * 8 + (rq >> 3);       // bijective XCD swizzle
  int m0 = by * 64, n0 = bx * 64;
  f32x4 acc[2][2] = {};
  gemm_core<64, 64, 2, 2>(aout, woT, arena, arena + 8192, m0, n0, tid, acc);
  int wr = (wave >> 1) * 32, wc = (wave & 1) * 32;
#pragma unroll
  for (int m = 0; m < 2; ++m)
#pragma unroll
    for (int n = 0; n < 2; ++n)
#pragma unroll
      for (int r = 0; r < 4; ++r) {
        int row = m0 + wr + m * 16 + ((lane >> 4) << 2) + r;
        int col = n0 + wc + n * 16 + (lane & 15);
        out[(size_t)row * 512 + col] = acc[m][n][r] + b_out[col];
      }
}

// ---------------- mega kernel (cooperative, persistent-LDS merge) ------------
__global__ __launch_bounds__(256, 2) void mega_k(
    const float* __restrict__ x, const float* __restrict__ gamma,
    const float* __restrict__ w_qkv, const float* __restrict__ b_qkv,
    const float* __restrict__ w_a, const float* __restrict__ b_a,
    const float* __restrict__ w_out, const float* __restrict__ b_out,
    float* __restrict__ out,
    short* __restrict__ xnb, short* __restrict__ wT, short* __restrict__ woT,
    short* __restrict__ qkvb, float* __restrict__ araw, float* __restrict__ csum,
    short* __restrict__ Sbuf, short* __restrict__ aout) {
  __shared__ __align__(16) char arena[32768];
  cg::grid_group grid = cg::this_grid();
  const int bid = blockIdx.x, tid = threadIdx.x;
  const int lane = tid & 63, wave = tid >> 6;

  // ---- S1: prep ----
  for (int u = bid; u < 2304; u += 512)
    st_prep(u, tid, arena, x, gamma, xnb, w_qkv, w_a, w_out, wT, woT);
  __threadfence(); grid.sync();

  // ---- S2: gemm0 ----
  st_gemm0(bid, tid, arena, xnb, wT, qkvb, b_qkv, b_a, araw, csum);
  __threadfence(); grid.sync();

  // ---- S3: gates -> LDS (qL,kR,kT,vTl) + kstate + local causal attention ---
  const int chunk = bid & 31, bh = bid >> 5;
  const int d = lane;
  char* qL  = arena;            // q2 row-major swz   [persists to S4+5]
  char* kR  = arena + 8192;     // k2 row-major swz   [S4+5 reuses for Spre]
  char* kT  = arena + 16384;    // k2^T swz           [reused for P]
  char* vTl = arena + 24576;    // v^T swz
  f32x4 accO[4] = {};
  {
    float (*wsum)[64] = reinterpret_cast<float (*)[64]>(kR);  // pre-gate scratch
    float pre = csum_prefix(csum, bh, chunk, d);
    const float* ap = araw + ((size_t)bh * 2048 + chunk * 64 + wave * 16) * 64 + d;
    float la[16]; float run = 0.f;
#pragma unroll
    for (int rr = 0; rr < 16; ++rr) {
      float xv = ap[rr * 64];
      float a = 1.f / (1.f + expf(-xv));
      a = fminf(fmaxf(a, 1e-10f), 1.f);
      run += logf(a);
      la[rr] = run;
    }
    wsum[wave][d] = run;
    __syncthreads();
#pragma unroll
    for (int w = 0; w < 3; ++w) if (w < wave) pre += wsum[w][d];
    __syncthreads();           // wsum reads done before kR is overwritten
    const size_t WS = (size_t)2 * 8 * 2048 * 64;
    size_t base = ((size_t)bh * 2048 + chunk * 64 + wave * 16) * 64 + d;
#pragma unroll 4
    for (int rr = 0; rr < 16; ++rr) {
      int r = wave * 16 + rr;
      float g = expf(pre + la[rr]);            // a_cum
      float gi = 1.f / fmaxf(g, 1e-8f);        // a_cum_inv
      float qv = b2f((unsigned short)qkvb[base + rr * 64]);
      float kv = b2f((unsigned short)qkvb[base + WS + rr * 64]);
      short vb = qkvb[base + 2 * WS + rr * 64];
      unsigned short qb = f2b(qv * 0.125f * g);   // SCALE = 64^-0.5
      unsigned short kb = f2b(kv * gi);
      // row-major swz writes
      int adr = ((r << 7) + (d << 1)) ^ ((r & 7) << 4);
      *reinterpret_cast<short*>(qL + adr) = (short)qb;
      *reinterpret_cast<short*>(kR + adr) = (short)kb;
      // transposed swz writes
      int adt = ((d << 7) + (r << 1)) ^ ((d & 7) << 4);
      *reinterpret_cast<short*>(kT  + adt) = (short)kb;
      *reinterpret_cast<short*>(vTl + adt) = vb;
    }
    __syncthreads();
    // kstate: S^T[dd][d'] = sum_j v[j][dd] k2[j][d']
    f32x4 sacc[4] = {};
#pragma unroll
    for (int kk = 0; kk < 2; ++kk) {
      int arow = wave * 16 + (lane & 15);
      int aad = ((arow << 7) + kk * 64 + ((lane >> 4) << 4)) ^ ((arow & 7) << 4);
      s8v av = *reinterpret_cast<const s8v*>(vTl + aad);
#pragma unroll
      for (int n = 0; n < 4; ++n) {
        int brow = n * 16 + (lane & 15);
        int bad = ((brow << 7) + kk * 64 + ((lane >> 4) << 4)) ^ ((brow & 7) << 4);
        sacc[n] = mfma16(av, *reinterpret_cast<const s8v*>(kT + bad), sacc[n]);
      }
    }
    short* Sp = Sbuf + ((size_t)bh * 32 + chunk) * 4096;
#pragma unroll
    for (int n = 0; n < 4; ++n)
#pragma unroll
      for (int r = 0; r < 4; ++r)
        Sp[(wave * 16 + ((lane >> 4) << 2) + r) * 64 + n * 16 + (lane & 15)] = (short)f2b(sacc[n][r]);
    // scores: sim[i][j] = q2[i]·k2[j]
    f32x4 accS[4] = {};
#pragma unroll
    for (int kk = 0; kk < 2; ++kk) {
      int arow = wave * 16 + (lane & 15);
      int aad = ((arow << 7) + kk * 64 + ((lane >> 4) << 4)) ^ ((arow & 7) << 4);
      s8v aq = *reinterpret_cast<const s8v*>(qL + aad);
#pragma unroll
      for (int n = 0; n < 4; ++n) {
        int brow = n * 16 + (lane & 15);
        int bad = ((brow << 7) + kk * 64 + ((lane >> 4) << 4)) ^ ((brow & 7) << 4);
        accS[n] = mfma16(aq, *reinterpret_cast<const s8v*>(kR + bad), accS[n]);
      }
    }
    __syncthreads();           // kT reads (kstate) done before P overwrites
#pragma unroll
    for (int n = 0; n < 4; ++n)
#pragma unroll
      for (int r = 0; r < 4; ++r) {
        int i = wave * 16 + ((lane >> 4) << 2) + r;
        int j = n * 16 + (lane & 15);
        float v = (j <= i) ? accS[n][r] : 0.f;
        int ad = ((i << 7) + (j << 1)) ^ ((i & 7) << 4);
        *reinterpret_cast<short*>(kT + ad) = (short)f2b(v);
      }
    __syncthreads();
    // PV: accO[i][d'] = sum_j P[i][j] v[j][d']
#pragma unroll
    for (int kk = 0; kk < 2; ++kk) {
      int arow = wave * 16 + (lane & 15);
      int aad = ((arow << 7) + kk * 64 + ((lane >> 4) << 4)) ^ ((arow & 7) << 4);
      s8v ap = *reinterpret_cast<const s8v*>(kT + aad);
#pragma unroll
      for (int n = 0; n < 4; ++n) {
        int brow = n * 16 + (lane & 15);
        int bad = ((brow << 7) + kk * 64 + ((lane >> 4) << 4)) ^ ((brow & 7) << 4);
        accO[n] = mfma16(ap, *reinterpret_cast<const s8v*>(vTl + bad), accO[n]);
      }
    }
  }
  __threadfence(); grid.sync();

  // ---- S4+S5 merged: per-block Spre (fp32 sum of Sbuf[c<chunk], same order
  //      as st_sprefix -> bit-identical) -> bf16 LDS; accO += q@Spre; aout ---
  {
    char* LS = kR;             // reuse kR area (dead since S3's accS MFMA)
    int srow = tid >> 2, scol0 = (tid & 3) * 16;
    const short* Sb = Sbuf + (size_t)bh * 32 * 4096 + srow * 64 + scol0;
    float acc0[8] = {}, acc1[8] = {};
#pragma unroll
    for (int c = 0; c < 32; ++c) {
      if (c < chunk) {         // uniform branch; loads independent across c
        s8v v0 = *reinterpret_cast<const s8v*>(Sb + (size_t)c * 4096);
        s8v v1 = *reinterpret_cast<const s8v*>(Sb + (size_t)c * 4096 + 8);
#pragma unroll
        for (int j = 0; j < 8; ++j) {
          acc0[j] += b2f((unsigned short)v0[j]);
          acc1[j] += b2f((unsigned short)v1[j]);
        }
      }
    }
    s8v o0, o1;
#pragma unroll
    for (int j = 0; j < 8; ++j) {
      o0[j] = (short)f2b(acc0[j]);
      o1[j] = (short)f2b(acc1[j]);
    }
    int byte0 = (srow << 7) + (scol0 << 1);     // 32B-aligned
    int sw = (srow & 7) << 4;
    *reinterpret_cast<s8v*>(LS + ((byte0)      ^ sw)) = o0;
    *reinterpret_cast<s8v*>(LS + ((byte0 + 16) ^ sw)) = o1;
    __syncthreads();
#pragma unroll
    for (int kk = 0; kk < 2; ++kk) {
      int arow = wave * 16 + (lane & 15);
      int aad = ((arow << 7) + kk * 64 + ((lane >> 4) << 4)) ^ ((arow & 7) << 4);
      s8v aq = *reinterpret_cast<const s8v*>(qL + aad);
#pragma unroll
      for (int n = 0; n < 4; ++n) {
        int brow = n * 16 + (lane & 15);
        int bad = ((brow << 7) + kk * 64 + ((lane >> 4) << 4)) ^ ((brow & 7) << 4);
        accO[n] = mfma16(aq, *reinterpret_cast<const s8v*>(LS + bad), accO[n]);
      }
    }
    int b = bh >> 3, h = bh & 7;
#pragma unroll
    for (int n = 0; n < 4; ++n)
#pragma unroll
      for (int r = 0; r < 4; ++r) {
        int i = wave * 16 + ((lane >> 4) << 2) + r;
        int col = h * 64 + n * 16 + (lane & 15);
        size_t row = (size_t)b * 2048 + chunk * 64 + i;
        aout[row * 512 + col] = (short)f2b(accO[n][r]);
      }
  }
  __threadfence(); grid.sync();

  // ---- S6: gemm1 ----
  st_gemm1(bid, tid, arena, aout, woT, out, b_out);
}

// ---------------- fallback wrappers (R8 proven path) -------------------------
__global__ __launch_bounds__(256) void prep_k(const float* x, const float* gamma,
    short* xnb, const float* w_qkv, const float* w_a, const float* w_out,
    short* wT, short* woT) {
  __shared__ __align__(16) char arena[4224];
  st_prep(blockIdx.x, threadIdx.x, arena, x, gamma, xnb, w_qkv, w_a, w_out, wT, woT);
}
__global__ __launch_bounds__(256) void gemm0_k(const short* xnb, const short* wT,
    short* qkvb, const float* b_qkv, const float* b_a, float* araw, float* csum) {
  __shared__ __align__(16) char arena[32768];
  st_gemm0(blockIdx.x, threadIdx.x, arena, xnb, wT, qkvb, b_qkv, b_a, araw, csum);
}
__global__ __launch_bounds__(256) void scan2_k(const short* qkvb, const float* araw,
    const float* csum, short* q2, short* k2, short* vT, short* Sbuf) {
  __shared__ __align__(16) char arena[32768];
  st_scan2(blockIdx.x, threadIdx.x, arena, qkvb, araw, csum, q2, k2, vT, Sbuf);
}
__global__ __launch_bounds__(256) void sprefix_k(const short* Sbuf, short* Spre) {
  st_sprefix(blockIdx.x, threadIdx.x, Sbuf, Spre);
}
__global__ __launch_bounds__(256) void attnk_k(const short* q2, const short* k2,
    const short* vT, const short* Spre, short* aout) {
  __shared__ __align__(16) char arena[32768];
  st_attnk(blockIdx.x, threadIdx.x, arena, q2, k2, vT, Spre, aout);
}
__global__ __launch_bounds__(256) void gemm1_k(const short* aout, const short* woT,
    float* out, const float* b_out) {
  __shared__ __align__(16) char arena[16384];
  st_gemm1(blockIdx.x, threadIdx.x, arena, aout, woT, out, b_out);
}

// ---------------------------------------------------------------------------
extern "C" void kernel_launch(void* const* d_in, const int* in_sizes, int n_in,
                              void* d_out, int out_size, void* d_ws, size_t ws_size,
                              hipStream_t stream) {
  const float* x     = (const float*)d_in[0];
  const float* gamma = (const float*)d_in[1];
  const float* w_qkv = (const float*)d_in[2];
  const float* b_qkv = (const float*)d_in[3];
  const float* w_a   = (const float*)d_in[4];
  const float* b_a   = (const float*)d_in[5];
  const float* w_out = (const float*)d_in[6];
  const float* b_out = (const float*)d_in[7];
  float* out = (float*)d_out;
  char* ws = (char*)d_ws;

  const size_t MB = 1u << 20;
  short* xnb  = (short*)(ws);                 // 4 MiB   [4096][512] bf16
  short* wT   = (short*)(ws + 4  * MB);       // 2 MiB   [2048][512] bf16
  short* woT  = (short*)(ws + 6  * MB);       // 0.5 MiB [512][512]  bf16
  short* qkvb = (short*)(ws + 7  * MB);       // 12 MiB  [3][2][8][2048][64] bf16
  float* araw = (float*)(ws + 19 * MB);       // 8 MiB   [16][2048][64] f32
  float* csum = (float*)(ws + 27 * MB);       // 128 KiB [16][32][64] f32
  short* Sbuf = (short*)(ws + 28 * MB);       // 4 MiB   [16][32][64][64] bf16
  short* aout = (short*)(ws + 32 * MB);       // 4 MiB   [4096][512] bf16
  // fallback-only buffers:
  short* Spre = (short*)(ws + 36 * MB);       // 4 MiB
  short* q2   = (short*)(ws + 40 * MB);       // 4 MiB
  short* k2   = (short*)(ws + 44 * MB);       // 4 MiB
  short* vT   = (short*)(ws + 48 * MB);       // 4 MiB

  int dev = 0; (void)hipGetDevice(&dev);
  int coop = 0;
  (void)hipDeviceGetAttribute(&coop, hipDeviceAttributeCooperativeLaunch, dev);
  int nb = 0;
  (void)hipOccupancyMaxActiveBlocksPerMultiprocessor(&nb, mega_k, 256, 0);

  hipError_t err = hipErrorUnknown;
  if (coop && nb >= 2) {
    void* args[] = {&x, &gamma, &w_qkv, &b_qkv, &w_a, &b_a, &w_out, &b_out,
                    &out, &xnb, &wT, &woT, &qkvb, &araw, &csum,
                    &Sbuf, &aout};
    err = hipLaunchCooperativeKernel((void*)mega_k, dim3(512), dim3(256), args, 0, stream);
  }
  if (err != hipSuccess) {
    prep_k   <<<2304, 256, 0, stream>>>(x, gamma, xnb, w_qkv, w_a, w_out, wT, woT);
    gemm0_k  <<<512,  256, 0, stream>>>(xnb, wT, qkvb, b_qkv, b_a, araw, csum);
    scan2_k  <<<512,  256, 0, stream>>>(qkvb, araw, csum, q2, k2, vT, Sbuf);
    sprefix_k<<<256,  256, 0, stream>>>(Sbuf, Spre);
    attnk_k  <<<512,  256, 0, stream>>>(q2, k2, vT, Spre, aout);
    gemm1_k  <<<512,  256, 0, stream>>>(aout, woT, out, b_out);
  }
}

// Round 12
// 59.682 us; speedup vs baseline: 1.1920x; 1.0296x over previous
//
#include <hip/hip_runtime.h>
#include <hip/hip_cooperative_groups.h>

// ---------------------------------------------------------------------------
// CausalFullAttention (decay-gated causal linear attention), MI355X gfx950
// b=2, n=2048, DIM=512, HEADS=8, DIM_HEAD=64
// R12: 4 blocks/CU (grid 1024, launch_bounds(256,4)):
//   S2 gemm0 re-tiled 128x64 (1024 tiles, 4x1 waves, LDS colsum epilogue),
//   S6 gemm1 re-tiled 64x32 (1024 tiles), S1 2.25 rounds,
//   S3/S45 duplicated across block pairs (unit = bid & 511, same-value writes).
// ---------------------------------------------------------------------------

namespace cg = cooperative_groups;

using s8v   = __attribute__((ext_vector_type(8))) short;   // 8 x bf16 bits
using f32x4 = __attribute__((ext_vector_type(4))) float;

__device__ __forceinline__ unsigned short f2b(float f) {
  unsigned int u = __builtin_bit_cast(unsigned int, f);
  u += 0x7FFFu + ((u >> 16) & 1u);          // RNE
  return (unsigned short)(u >> 16);
}
__device__ __forceinline__ float b2f(unsigned short b) {
  unsigned int u = ((unsigned int)b) << 16;
  return __builtin_bit_cast(float, u);
}
__device__ __forceinline__ f32x4 mfma16(s8v a, s8v b, f32x4 c) {
  return __builtin_amdgcn_mfma_f32_16x16x32_bf16(a, b, c, 0, 0, 0);
}
__device__ __forceinline__ void gload16(const void* g, void* l) {
  __builtin_amdgcn_global_load_lds(
      (const __attribute__((address_space(1))) void*)g,
      (__attribute__((address_space(3))) void*)l, 16, 0, 0);
}

// ---------------- stage: prep (rmsnorm u<1024 | wtrans u>=1024) --------------
__device__ __forceinline__ void st_prep(int u, int tid, char* arena,
    const float* __restrict__ x, const float* __restrict__ gamma,
    short* __restrict__ xnb,
    const float* __restrict__ w_qkv, const float* __restrict__ w_a,
    const float* __restrict__ w_out,
    short* __restrict__ wT, short* __restrict__ woT) {
  int lane = tid & 63, wave = tid >> 6;
  if (u < 1024) {
    int row = u * 4 + wave;
    const float4* xp = reinterpret_cast<const float4*>(x + (size_t)row * 512 + lane * 8);
    float4 v0 = xp[0], v1 = xp[1];
    float ss = v0.x*v0.x + v0.y*v0.y + v0.z*v0.z + v0.w*v0.w
             + v1.x*v1.x + v1.y*v1.y + v1.z*v1.z + v1.w*v1.w;
#pragma unroll
    for (int off = 32; off > 0; off >>= 1) ss += __shfl_xor(ss, off, 64);
    float s = 22.627416997969522f / fmaxf(sqrtf(ss), 1e-12f);
    const float* g = gamma + lane * 8;
    float vals[8] = {v0.x, v0.y, v0.z, v0.w, v1.x, v1.y, v1.z, v1.w};
    s8v o;
#pragma unroll
    for (int j = 0; j < 8; ++j) o[j] = (short)f2b(vals[j] * s * g[j]);
    *reinterpret_cast<s8v*>(xnb + (size_t)row * 512 + lane * 8) = o;
  } else {
    float (*t)[33] = reinterpret_cast<float (*)[33]>(arena);
    int id = u - 1024;
    int bx = id % 80, k0 = (id / 80) * 32;
    const float* src; short* dst; int N, n0;
    if (bx < 48)      { src = w_qkv; dst = wT;                      N = 1536; n0 = bx * 32; }
    else if (bx < 64) { src = w_a;   dst = wT + (size_t)1536 * 512; N = 512;  n0 = (bx - 48) * 32; }
    else              { src = w_out; dst = woT;                     N = 512;  n0 = (bx - 64) * 32; }
    int tx = tid & 31, ty = tid >> 5;
    __syncthreads();   // prior arena use complete
#pragma unroll
    for (int i = 0; i < 4; ++i)
      t[ty + 8 * i][tx] = src[(size_t)(k0 + ty + 8 * i) * N + n0 + tx];
    __syncthreads();
#pragma unroll
    for (int i = 0; i < 4; ++i)
      dst[(size_t)(n0 + ty + 8 * i) * 512 + k0 + tx] = (short)f2b(t[tx][ty + 8 * i]);
  }
}

// ---------------- shared single-buffered GEMM core (m97 structure) -----------
// WR x WC wave grid (WR*WC = 4 waves).
template <int BM, int BN, int WR, int WC>
__device__ __forceinline__ void gemm_core(const short* __restrict__ A,
                                          const short* __restrict__ Bm,
                                          char* LA, char* LB,
                                          int m0, int n0, int tid,
                                          f32x4 (&acc)[BM / WR / 16][BN / WC / 16]) {
  constexpr int WM = BM / WR, WN = BN / WC, FM = WM / 16, FN = WN / 16;
  const int lane = tid & 63, wave = tid >> 6;
  const int wr = (wave / WC) * WM, wc = (wave % WC) * WN;
#pragma unroll 1
  for (int t = 0; t < 8; ++t) {            // K = 512, BK = 64
    const int k0 = t * 64;
#pragma unroll
    for (int r = 0; r < BM / 32; ++r) {
      int o = r * 4096 + tid * 16;
      int row = o >> 7;
      int ce = (((o & 127) ^ ((row & 7) << 4)) >> 1);   // pre-swizzled src col
      gload16(A + (size_t)(m0 + row) * 512 + k0 + ce, LA + o);
    }
#pragma unroll
    for (int r = 0; r < BN / 32; ++r) {
      int o = r * 4096 + tid * 16;
      int row = o >> 7;
      int ce = (((o & 127) ^ ((row & 7) << 4)) >> 1);
      gload16(Bm + (size_t)(n0 + row) * 512 + k0 + ce, LB + o);
    }
    __syncthreads();                       // tile ready (vmcnt drained)
#pragma unroll
    for (int kk = 0; kk < 2; ++kk) {
      s8v af[FM], bf[FN];
#pragma unroll
      for (int m = 0; m < FM; ++m) {
        int row = wr + m * 16 + (lane & 15);
        int ad = ((row << 7) + kk * 64 + ((lane >> 4) << 4)) ^ ((row & 7) << 4);
        af[m] = *reinterpret_cast<const s8v*>(LA + ad);
      }
#pragma unroll
      for (int n = 0; n < FN; ++n) {
        int row = wc + n * 16 + (lane & 15);
        int ad = ((row << 7) + kk * 64 + ((lane >> 4) << 4)) ^ ((row & 7) << 4);
        bf[n] = *reinterpret_cast<const s8v*>(LB + ad);
      }
#pragma unroll
      for (int m = 0; m < FM; ++m)
#pragma unroll
        for (int n = 0; n < FN; ++n)
          acc[m][n] = mfma16(af[m], bf[n], acc[m][n]);
    }
    if (t + 1 < 8) __syncthreads();        // reads done before next overwrite
  }
}

// ---------------- stage: gemm<0> 128x64 tiles (1024) + epilogues -------------
__device__ __forceinline__ void st_gemm0(int vid, int tid, char* arena,
    const short* __restrict__ xnb, const short* __restrict__ wT,
    short* __restrict__ qkvb, const float* __restrict__ b_qkv,
    const float* __restrict__ b_a, float* __restrict__ araw,
    float* __restrict__ csum) {
  const int lane = tid & 63, wave = tid >> 6;
  // 32x32 tile grid, bijective XCD swizzle
  int xcd = vid & 7, rq = vid >> 3;
  int bx = rq & 31, by = xcd * 4 + (rq >> 5);
  int m0 = by * 128, n0 = bx * 64;
  f32x4 acc[2][4] = {};
  gemm_core<128, 64, 4, 1>(xnb, wT, arena, arena + 16384, m0, n0, tid, acc);
  int wr = wave * 32;
  if (n0 < 1536) {
#pragma unroll
    for (int m = 0; m < 2; ++m)
#pragma unroll
      for (int n = 0; n < 4; ++n)
#pragma unroll
        for (int r = 0; r < 4; ++r) {
          int row = m0 + wr + m * 16 + ((lane >> 4) << 2) + r;
          int col = n0 + n * 16 + (lane & 15);
          float v = acc[m][n][r] + b_qkv[col];
          int w = col >> 9, h = (col >> 6) & 7, d = col & 63;
          int b = row >> 11, nn = row & 2047;
          qkvb[((((size_t)(w * 2 + b)) * 8 + h) * 2048 + nn) * 64 + d] = (short)f2b(v);
        }
  } else {
    __syncthreads();           // all LDS reads done; arena free for WSUM
    float (*WSUM)[64] = reinterpret_cast<float (*)[64]>(arena);
    float cs[4] = {};
    int b = m0 >> 11;
#pragma unroll
    for (int m = 0; m < 2; ++m)
#pragma unroll
      for (int n = 0; n < 4; ++n)
#pragma unroll
        for (int r = 0; r < 4; ++r) {
          int row = m0 + wr + m * 16 + ((lane >> 4) << 2) + r;
          int gc = n0 + n * 16 + (lane & 15) - 1536;
          int h = gc >> 6, d = gc & 63, nn = row & 2047;
          float xv = acc[m][n][r] + b_a[gc];
          araw[((size_t)(b * 8 + h) * 2048 + nn) * 64 + d] = xv;
          float a = 1.f / (1.f + expf(-xv));
          a = fminf(fmaxf(a, 1e-10f), 1.f);
          cs[n] += logf(a);
        }
#pragma unroll
    for (int n = 0; n < 4; ++n) {          // sum the 4 row-subgroups of wave
      cs[n] += __shfl_xor(cs[n], 16, 64);
      cs[n] += __shfl_xor(cs[n], 32, 64);
    }
    if (lane < 16) {
#pragma unroll
      for (int n = 0; n < 4; ++n) WSUM[wave][n * 16 + lane] = cs[n];
    }
    __syncthreads();
    if (tid < 128) {                       // chunk cl = waves {2cl, 2cl+1}
      int cl = tid >> 6, col = tid & 63;
      float s = WSUM[2 * cl][col] + WSUM[2 * cl + 1][col];
      int h = (n0 - 1536) >> 6;
      int chunkg = ((m0 & 2047) >> 6) + cl;
      csum[(((size_t)(b * 8 + h)) * 32 + chunkg) * 64 + col] = s;
    }
  }
}

// chunk-prefix over csum with fixed-32 unroll (independent loads, masked add)
__device__ __forceinline__ float csum_prefix(const float* __restrict__ csum,
                                             int bh, int chunk, int d) {
  float pre = 0.f;
#pragma unroll
  for (int c = 0; c < 32; ++c) {
    float cv = csum[((size_t)bh * 32 + c) * 64 + d];
    pre += (c < chunk) ? cv : 0.f;
  }
  return pre;
}

// ---------------- fallback stages (R8 path: q2/k2/vT materialized) -----------
__device__ __forceinline__ void st_scan2(int vid, int tid, char* arena,
    const short* __restrict__ qkvb, const float* __restrict__ araw,
    const float* __restrict__ csum, short* __restrict__ q2,
    short* __restrict__ k2, short* __restrict__ vT, short* __restrict__ Sbuf) {
  int chunk = vid & 31, bh = vid >> 5;
  int lane = tid & 63, wave = tid >> 6, d = lane;
  short (*kL)[64] = reinterpret_cast<short (*)[64]>(arena);
  short (*vL)[64] = reinterpret_cast<short (*)[64]>(arena + 8192);
  char* kT  = arena + 16384;
  char* vTl = arena + 24576;
  float (*wsum)[64] = reinterpret_cast<float (*)[64]>(arena + 16384);
  float pre = csum_prefix(csum, bh, chunk, d);
  const float* ap = araw + ((size_t)bh * 2048 + chunk * 64 + wave * 16) * 64 + d;
  float la[16]; float run = 0.f;
#pragma unroll
  for (int rr = 0; rr < 16; ++rr) {
    float xv = ap[rr * 64];
    float a = 1.f / (1.f + expf(-xv));
    a = fminf(fmaxf(a, 1e-10f), 1.f);
    run += logf(a);
    la[rr] = run;
  }
  wsum[wave][d] = run;
  __syncthreads();
#pragma unroll
  for (int w = 0; w < 3; ++w) if (w < wave) pre += wsum[w][d];
  const size_t WS = (size_t)2 * 8 * 2048 * 64;
  size_t base = ((size_t)bh * 2048 + chunk * 64 + wave * 16) * 64 + d;
#pragma unroll 4
  for (int rr = 0; rr < 16; ++rr) {
    int r = wave * 16 + rr;
    float g = expf(pre + la[rr]);
    float gi = 1.f / fmaxf(g, 1e-8f);
    float qv = b2f((unsigned short)qkvb[base + rr * 64]);
    float kv = b2f((unsigned short)qkvb[base + WS + rr * 64]);
    short vb = qkvb[base + 2 * WS + rr * 64];
    q2[base + rr * 64] = (short)f2b(qv * 0.125f * g);
    unsigned short kb = f2b(kv * gi);
    k2[base + rr * 64] = (short)kb;
    kL[r][d] = (short)kb;
    vL[r][d] = vb;
  }
  __syncthreads();
  short* vTrow = vT + ((size_t)bh * 64 + d) * 2048 + chunk * 64;
#pragma unroll
  for (int gg = 0; gg < 2; ++gg) {
    int g8 = wave + gg * 4;
    s8v pk, pv;
#pragma unroll
    for (int j = 0; j < 8; ++j) { pk[j] = kL[g8 * 8 + j][d]; pv[j] = vL[g8 * 8 + j][d]; }
    *reinterpret_cast<s8v*>(vTrow + g8 * 8) = pv;
    int ad = ((d << 7) + g8 * 16) ^ ((d & 7) << 4);
    *reinterpret_cast<s8v*>(kT  + ad) = pk;
    *reinterpret_cast<s8v*>(vTl + ad) = pv;
  }
  __syncthreads();
  f32x4 acc[4] = {};
#pragma unroll
  for (int kk = 0; kk < 2; ++kk) {
    int arow = wave * 16 + (lane & 15);
    int aad = ((arow << 7) + kk * 64 + ((lane >> 4) << 4)) ^ ((arow & 7) << 4);
    s8v av = *reinterpret_cast<const s8v*>(vTl + aad);
#pragma unroll
    for (int n = 0; n < 4; ++n) {
      int brow = n * 16 + (lane & 15);
      int bad = ((brow << 7) + kk * 64 + ((lane >> 4) << 4)) ^ ((brow & 7) << 4);
      acc[n] = mfma16(av, *reinterpret_cast<const s8v*>(kT + bad), acc[n]);
    }
  }
  short* Sp = Sbuf + ((size_t)bh * 32 + chunk) * 4096;
#pragma unroll
  for (int n = 0; n < 4; ++n)
#pragma unroll
    for (int r = 0; r < 4; ++r)
      Sp[(wave * 16 + ((lane >> 4) << 2) + r) * 64 + n * 16 + (lane & 15)] = (short)f2b(acc[n][r]);
}

__device__ __forceinline__ void st_sprefix(int vid, int tid,
    const short* __restrict__ Sbuf, short* __restrict__ Spre) {
  int bh = vid >> 4;
  int e = ((vid & 15) << 8) + tid;
  size_t base = (size_t)bh * 32 * 4096 + e;
  unsigned short v[32];
#pragma unroll
  for (int c = 0; c < 32; ++c)
    v[c] = (unsigned short)Sbuf[base + (size_t)c * 4096];
  float acc = 0.f;
#pragma unroll
  for (int c = 0; c < 32; ++c) {
    Spre[base + (size_t)c * 4096] = (short)f2b(acc);
    acc += b2f(v[c]);
  }
}

__device__ __forceinline__ void st_attnk(int vid, int tid, char* arena,
    const short* __restrict__ q2, const short* __restrict__ k2,
    const short* __restrict__ vT, const short* __restrict__ Spre,
    short* __restrict__ aout) {
  int chunk = vid & 31, bh = vid >> 5;
  int lane = tid & 63, wave = tid >> 6;
  char* LQ = arena;              // later reused for P
  char* LK = arena + 8192;
  char* LV = arena + 16384;
  char* LS = arena + 24576;
#pragma unroll
  for (int rr = 0; rr < 2; ++rr) {
    int o = rr * 4096 + tid * 16;
    int row = o >> 7;
    int ce = (((o & 127) ^ ((row & 7) << 4)) >> 1);
    gload16(q2   + ((size_t)bh * 2048 + chunk * 64 + row) * 64 + ce, LQ + o);
    gload16(k2   + ((size_t)bh * 2048 + chunk * 64 + row) * 64 + ce, LK + o);
    gload16(vT   + ((size_t)bh * 64 + row) * 2048 + chunk * 64 + ce, LV + o);
    gload16(Spre + (((size_t)bh * 32 + chunk) * 64 + row) * 64 + ce, LS + o);
  }
  __syncthreads();
  f32x4 accS[4] = {}, accO[4] = {};
#pragma unroll
  for (int kk = 0; kk < 2; ++kk) {
    int arow = wave * 16 + (lane & 15);
    int aad = ((arow << 7) + kk * 64 + ((lane >> 4) << 4)) ^ ((arow & 7) << 4);
    s8v aq = *reinterpret_cast<const s8v*>(LQ + aad);
#pragma unroll
    for (int n = 0; n < 4; ++n) {
      int brow = n * 16 + (lane & 15);
      int bad = ((brow << 7) + kk * 64 + ((lane >> 4) << 4)) ^ ((brow & 7) << 4);
      accS[n] = mfma16(aq, *reinterpret_cast<const s8v*>(LK + bad), accS[n]);
      accO[n] = mfma16(aq, *reinterpret_cast<const s8v*>(LS + bad), accO[n]);
    }
  }
  __syncthreads();
#pragma unroll
  for (int n = 0; n < 4; ++n)
#pragma unroll
    for (int r = 0; r < 4; ++r) {
      int i = wave * 16 + ((lane >> 4) << 2) + r;
      int j = n * 16 + (lane & 15);
      float v = (j <= i) ? accS[n][r] : 0.f;
      int ad = ((i << 7) + (j << 1)) ^ ((i & 7) << 4);
      *reinterpret_cast<short*>(LQ + ad) = (short)f2b(v);
    }
  __syncthreads();
#pragma unroll
  for (int kk = 0; kk < 2; ++kk) {
    int arow = wave * 16 + (lane & 15);
    int aad = ((arow << 7) + kk * 64 + ((lane >> 4) << 4)) ^ ((arow & 7) << 4);
    s8v ap = *reinterpret_cast<const s8v*>(LQ + aad);
#pragma unroll
    for (int n = 0; n < 4; ++n) {
      int brow = n * 16 + (lane & 15);
      int bad = ((brow << 7) + kk * 64 + ((lane >> 4) << 4)) ^ ((brow & 7) << 4);
      accO[n] = mfma16(ap, *reinterpret_cast<const s8v*>(LV + bad), accO[n]);
    }
  }
  int b = bh >> 3, h = bh & 7;
#pragma unroll
  for (int n = 0; n < 4; ++n)
#pragma unroll
    for (int r = 0; r < 4; ++r) {
      int i = wave * 16 + ((lane >> 4) << 2) + r;
      int col = h * 64 + n * 16 + (lane & 15);
      size_t row = (size_t)b * 2048 + chunk * 64 + i;
      aout[row * 512 + col] = (short)f2b(accO[n][r]);
    }
}

// ---------------- stage: gemm<1> 64x32 tiles (1024) --------------------------
__device__ __forceinline__ void st_gemm1(int vid, int tid, char* arena,
    const short* __restrict__ aout, const short* __restrict__ woT,
    float* __restrict__ out, const float* __restrict__ b_out) {
  const int lane = tid & 63, wave = tid >> 6;
  int xcd = vid & 7, rq = vid >> 3;
  int bx = rq & 15, by = xcd * 8 + (rq >> 4);      // bijective, 64x16 grid
  int m0 = by * 64, n0 = bx * 32;
  f32x4 acc[1][2] = {};
  gemm_core<64, 32, 4, 1>(aout, woT, arena, arena + 8192, m0, n0, tid, acc);
  int wr = wave * 16;
#pragma unroll
  for (int n = 0; n < 2; ++n)
#pragma unroll
    for (int r = 0; r < 4; ++r) {
      int row = m0 + wr + ((lane >> 4) << 2) + r;
      int col = n0 + n * 16 + (lane & 15);
      out[(size_t)row * 512 + col] = acc[0][n][r] + b_out[col];
    }
}

// ---------------- mega kernel (cooperative, 4 blocks/CU) ---------------------
__global__ __launch_bounds__(256, 4) void mega_k(
    const float* __restrict__ x, const float* __restrict__ gamma,
    const float* __restrict__ w_qkv, const float* __restrict__ b_qkv,
    const float* __restrict__ w_a, const float* __restrict__ b_a,
    const float* __restrict__ w_out, const float* __restrict__ b_out,
    float* __restrict__ out,
    short* __restrict__ xnb, short* __restrict__ wT, short* __restrict__ woT,
    short* __restrict__ qkvb, float* __restrict__ araw, float* __restrict__ csum,
    short* __restrict__ Sbuf, short* __restrict__ aout) {
  __shared__ __align__(16) char arena[32768];
  cg::grid_group grid = cg::this_grid();
  const int bid = blockIdx.x, tid = threadIdx.x;
  const int lane = tid & 63, wave = tid >> 6;

  // ---- S1: prep (2304 units over 1024 blocks) ----
  for (int u = bid; u < 2304; u += 1024)
    st_prep(u, tid, arena, x, gamma, xnb, w_qkv, w_a, w_out, wT, woT);
  __threadfence(); grid.sync();

  // ---- S2: gemm0 (1024 tiles of 128x64) ----
  st_gemm0(bid, tid, arena, xnb, wT, qkvb, b_qkv, b_a, araw, csum);
  __threadfence(); grid.sync();

  // ---- S3: gates -> LDS + kstate + local causal attention (duplicated) ----
  const int unit = bid & 511;              // twin blocks compute identically
  const int chunk = unit & 31, bh = unit >> 5;
  const int d = lane;
  char* qL  = arena;            // q2 row-major swz   [persists to S4+5]
  char* kR  = arena + 8192;     // k2 row-major swz   [S4+5 reuses for Spre]
  char* kT  = arena + 16384;    // k2^T swz           [reused for P]
  char* vTl = arena + 24576;    // v^T swz
  f32x4 accO[4] = {};
  {
    float (*wsum)[64] = reinterpret_cast<float (*)[64]>(kR);  // pre-gate scratch
    float pre = csum_prefix(csum, bh, chunk, d);
    const float* ap = araw + ((size_t)bh * 2048 + chunk * 64 + wave * 16) * 64 + d;
    float la[16]; float run = 0.f;
#pragma unroll
    for (int rr = 0; rr < 16; ++rr) {
      float xv = ap[rr * 64];
      float a = 1.f / (1.f + expf(-xv));
      a = fminf(fmaxf(a, 1e-10f), 1.f);
      run += logf(a);
      la[rr] = run;
    }
    wsum[wave][d] = run;
    __syncthreads();
#pragma unroll
    for (int w = 0; w < 3; ++w) if (w < wave) pre += wsum[w][d];
    __syncthreads();           // wsum reads done before kR is overwritten
    const size_t WS = (size_t)2 * 8 * 2048 * 64;
    size_t base = ((size_t)bh * 2048 + chunk * 64 + wave * 16) * 64 + d;
#pragma unroll 4
    for (int rr = 0; rr < 16; ++rr) {
      int r = wave * 16 + rr;
      float g = expf(pre + la[rr]);            // a_cum
      float gi = 1.f / fmaxf(g, 1e-8f);        // a_cum_inv
      float qv = b2f((unsigned short)qkvb[base + rr * 64]);
      float kv = b2f((unsigned short)qkvb[base + WS + rr * 64]);
      short vb = qkvb[base + 2 * WS + rr * 64];
      unsigned short qb = f2b(qv * 0.125f * g);   // SCALE = 64^-0.5
      unsigned short kb = f2b(kv * gi);
      int adr = ((r << 7) + (d << 1)) ^ ((r & 7) << 4);
      *reinterpret_cast<short*>(qL + adr) = (short)qb;
      *reinterpret_cast<short*>(kR + adr) = (short)kb;
      int adt = ((d << 7) + (r << 1)) ^ ((d & 7) << 4);
      *reinterpret_cast<short*>(kT  + adt) = (short)kb;
      *reinterpret_cast<short*>(vTl + adt) = vb;
    }
    __syncthreads();
    // kstate: S^T[dd][d'] = sum_j v[j][dd] k2[j][d']
    f32x4 sacc[4] = {};
#pragma unroll
    for (int kk = 0; kk < 2; ++kk) {
      int arow = wave * 16 + (lane & 15);
      int aad = ((arow << 7) + kk * 64 + ((lane >> 4) << 4)) ^ ((arow & 7) << 4);
      s8v av = *reinterpret_cast<const s8v*>(vTl + aad);
#pragma unroll
      for (int n = 0; n < 4; ++n) {
        int brow = n * 16 + (lane & 15);
        int bad = ((brow << 7) + kk * 64 + ((lane >> 4) << 4)) ^ ((brow & 7) << 4);
        sacc[n] = mfma16(av, *reinterpret_cast<const s8v*>(kT + bad), sacc[n]);
      }
    }
    short* Sp = Sbuf + ((size_t)bh * 32 + chunk) * 4096;
#pragma unroll
    for (int n = 0; n < 4; ++n)
#pragma unroll
      for (int r = 0; r < 4; ++r)
        Sp[(wave * 16 + ((lane >> 4) << 2) + r) * 64 + n * 16 + (lane & 15)] = (short)f2b(sacc[n][r]);
    // scores: sim[i][j] = q2[i]·k2[j]
    f32x4 accS[4] = {};
#pragma unroll
    for (int kk = 0; kk < 2; ++kk) {
      int arow = wave * 16 + (lane & 15);
      int aad = ((arow << 7) + kk * 64 + ((lane >> 4) << 4)) ^ ((arow & 7) << 4);
      s8v aq = *reinterpret_cast<const s8v*>(qL + aad);
#pragma unroll
      for (int n = 0; n < 4; ++n) {
        int brow = n * 16 + (lane & 15);
        int bad = ((brow << 7) + kk * 64 + ((lane >> 4) << 4)) ^ ((brow & 7) << 4);
        accS[n] = mfma16(aq, *reinterpret_cast<const s8v*>(kR + bad), accS[n]);
      }
    }
    __syncthreads();           // kT reads (kstate) done before P overwrites
#pragma unroll
    for (int n = 0; n < 4; ++n)
#pragma unroll
      for (int r = 0; r < 4; ++r) {
        int i = wave * 16 + ((lane >> 4) << 2) + r;
        int j = n * 16 + (lane & 15);
        float v = (j <= i) ? accS[n][r] : 0.f;
        int ad = ((i << 7) + (j << 1)) ^ ((i & 7) << 4);
        *reinterpret_cast<short*>(kT + ad) = (short)f2b(v);
      }
    __syncthreads();
    // PV: accO[i][d'] = sum_j P[i][j] v[j][d']
#pragma unroll
    for (int kk = 0; kk < 2; ++kk) {
      int arow = wave * 16 + (lane & 15);
      int aad = ((arow << 7) + kk * 64 + ((lane >> 4) << 4)) ^ ((arow & 7) << 4);
      s8v ap = *reinterpret_cast<const s8v*>(kT + aad);
#pragma unroll
      for (int n = 0; n < 4; ++n) {
        int brow = n * 16 + (lane & 15);
        int bad = ((brow << 7) + kk * 64 + ((lane >> 4) << 4)) ^ ((brow & 7) << 4);
        accO[n] = mfma16(ap, *reinterpret_cast<const s8v*>(vTl + bad), accO[n]);
      }
    }
  }
  __threadfence(); grid.sync();

  // ---- S4+S5 merged: per-block Spre -> bf16 LDS; accO += q@Spre; aout ------
  {
    char* LS = kR;             // reuse kR area (dead since S3's accS MFMA)
    int srow = tid >> 2, scol0 = (tid & 3) * 16;
    const short* Sb = Sbuf + (size_t)bh * 32 * 4096 + srow * 64 + scol0;
    float acc0[8] = {}, acc1[8] = {};
#pragma unroll
    for (int c = 0; c < 32; ++c) {
      if (c < chunk) {         // uniform branch; loads independent across c
        s8v v0 = *reinterpret_cast<const s8v*>(Sb + (size_t)c * 4096);
        s8v v1 = *reinterpret_cast<const s8v*>(Sb + (size_t)c * 4096 + 8);
#pragma unroll
        for (int j = 0; j < 8; ++j) {
          acc0[j] += b2f((unsigned short)v0[j]);
          acc1[j] += b2f((unsigned short)v1[j]);
        }
      }
    }
    s8v o0, o1;
#pragma unroll
    for (int j = 0; j < 8; ++j) {
      o0[j] = (short)f2b(acc0[j]);
      o1[j] = (short)f2b(acc1[j]);
    }
    int byte0 = (srow << 7) + (scol0 << 1);     // 32B-aligned
    int sw = (srow & 7) << 4;
    *reinterpret_cast<s8v*>(LS + ((byte0)      ^ sw)) = o0;
    *reinterpret_cast<s8v*>(LS + ((byte0 + 16) ^ sw)) = o1;
    __syncthreads();
#pragma unroll
    for (int kk = 0; kk < 2; ++kk) {
      int arow = wave * 16 + (lane & 15);
      int aad = ((arow << 7) + kk * 64 + ((lane >> 4) << 4)) ^ ((arow & 7) << 4);
      s8v aq = *reinterpret_cast<const s8v*>(qL + aad);
#pragma unroll
      for (int n = 0; n < 4; ++n) {
        int brow = n * 16 + (lane & 15);
        int bad = ((brow << 7) + kk * 64 + ((lane >> 4) << 4)) ^ ((brow & 7) << 4);
        accO[n] = mfma16(aq, *reinterpret_cast<const s8v*>(LS + bad), accO[n]);
      }
    }
    int b = bh >> 3, h = bh & 7;
#pragma unroll
    for (int n = 0; n < 4; ++n)
#pragma unroll
      for (int r = 0; r < 4; ++r) {
        int i = wave * 16 + ((lane >> 4) << 2) + r;
        int col = h * 64 + n * 16 + (lane & 15);
        size_t row = (size_t)b * 2048 + chunk * 64 + i;
        aout[row * 512 + col] = (short)f2b(accO[n][r]);
      }
  }
  __threadfence(); grid.sync();

  // ---- S6: gemm1 (1024 tiles of 64x32) ----
  st_gemm1(bid, tid, arena, aout, woT, out, b_out);
}

// ---------------- fallback wrappers (proven path, new shapes) ----------------
__global__ __launch_bounds__(256) void prep_k(const float* x, const float* gamma,
    short* xnb, const float* w_qkv, const float* w_a, const float* w_out,
    short* wT, short* woT) {
  __shared__ __align__(16) char arena[4224];
  st_prep(blockIdx.x, threadIdx.x, arena, x, gamma, xnb, w_qkv, w_a, w_out, wT, woT);
}
__global__ __launch_bounds__(256) void gemm0_k(const short* xnb, const short* wT,
    short* qkvb, const float* b_qkv, const float* b_a, float* araw, float* csum) {
  __shared__ __align__(16) char arena[24576];
  st_gemm0(blockIdx.x, threadIdx.x, arena, xnb, wT, qkvb, b_qkv, b_a, araw, csum);
}
__global__ __launch_bounds__(256) void scan2_k(const short* qkvb, const float* araw,
    const float* csum, short* q2, short* k2, short* vT, short* Sbuf) {
  __shared__ __align__(16) char arena[32768];
  st_scan2(blockIdx.x, threadIdx.x, arena, qkvb, araw, csum, q2, k2, vT, Sbuf);
}
__global__ __launch_bounds__(256) void sprefix_k(const short* Sbuf, short* Spre) {
  st_sprefix(blockIdx.x, threadIdx.x, Sbuf, Spre);
}
__global__ __launch_bounds__(256) void attnk_k(const short* q2, const short* k2,
    const short* vT, const short* Spre, short* aout) {
  __shared__ __align__(16) char arena[32768];
  st_attnk(blockIdx.x, threadIdx.x, arena, q2, k2, vT, Spre, aout);
}
__global__ __launch_bounds__(256) void gemm1_k(const short* aout, const short* woT,
    float* out, const float* b_out) {
  __shared__ __align__(16) char arena[12288];
  st_gemm1(blockIdx.x, threadIdx.x, arena, aout, woT, out, b_out);
}

// ---------------------------------------------------------------------------
extern "C" void kernel_launch(void* const* d_in, const int* in_sizes, int n_in,
                              void* d_out, int out_size, void* d_ws, size_t ws_size,
                              hipStream_t stream) {
  const float* x     = (const float*)d_in[0];
  const float* gamma = (const float*)d_in[1];
  const float* w_qkv = (const float*)d_in[2];
  const float* b_qkv = (const float*)d_in[3];
  const float* w_a   = (const float*)d_in[4];
  const float* b_a   = (const float*)d_in[5];
  const float* w_out = (const float*)d_in[6];
  const float* b_out = (const float*)d_in[7];
  float* out = (float*)d_out;
  char* ws = (char*)d_ws;

  const size_t MB = 1u << 20;
  short* xnb  = (short*)(ws);                 // 4 MiB   [4096][512] bf16
  short* wT   = (short*)(ws + 4  * MB);       // 2 MiB   [2048][512] bf16
  short* woT  = (short*)(ws + 6  * MB);       // 0.5 MiB [512][512]  bf16
  short* qkvb = (short*)(ws + 7  * MB);       // 12 MiB  [3][2][8][2048][64] bf16
  float* araw = (float*)(ws + 19 * MB);       // 8 MiB   [16][2048][64] f32
  float* csum = (float*)(ws + 27 * MB);       // 128 KiB [16][32][64] f32
  short* Sbuf = (short*)(ws + 28 * MB);       // 4 MiB   [16][32][64][64] bf16
  short* aout = (short*)(ws + 32 * MB);       // 4 MiB   [4096][512] bf16
  // fallback-only buffers:
  short* Spre = (short*)(ws + 36 * MB);       // 4 MiB
  short* q2   = (short*)(ws + 40 * MB);       // 4 MiB
  short* k2   = (short*)(ws + 44 * MB);       // 4 MiB
  short* vT   = (short*)(ws + 48 * MB);       // 4 MiB

  int dev = 0; (void)hipGetDevice(&dev);
  int coop = 0;
  (void)hipDeviceGetAttribute(&coop, hipDeviceAttributeCooperativeLaunch, dev);
  int nb = 0;
  (void)hipOccupancyMaxActiveBlocksPerMultiprocessor(&nb, mega_k, 256, 0);

  hipError_t err = hipErrorUnknown;
  if (coop && nb >= 4) {
    void* args[] = {&x, &gamma, &w_qkv, &b_qkv, &w_a, &b_a, &w_out, &b_out,
                    &out, &xnb, &wT, &woT, &qkvb, &araw, &csum,
                    &Sbuf, &aout};
    err = hipLaunchCooperativeKernel((void*)mega_k, dim3(1024), dim3(256), args, 0, stream);
  }
  if (err != hipSuccess) {
    prep_k   <<<2304, 256, 0, stream>>>(x, gamma, xnb, w_qkv, w_a, w_out, wT, woT);
    gemm0_k  <<<1024, 256, 0, stream>>>(xnb, wT, qkvb, b_qkv, b_a, araw, csum);
    scan2_k  <<<512,  256, 0, stream>>>(qkvb, araw, csum, q2, k2, vT, Sbuf);
    sprefix_k<<<256,  256, 0, stream>>>(Sbuf, Spre);
    attnk_k  <<<512,  256, 0, stream>>>(q2, k2, vT, Spre, aout);
    gemm1_k  <<<1024, 256, 0, stream>>>(aout, woT, out, b_out);
  }
}